// Round 1
// baseline (12995.003 us; speedup 1.0000x reference)
//
#include <hip/hip_runtime.h>

#define B64 64
#define SE 512
#define HD 1024
#define ED 512
#define NV 10000
#define TT 20
#define MM 1536
#define MASK_VALF -10000000.0f

// ---- workspace offsets (in floats) ----
#define OFF_XT    0                    // xT_lstm [1536][64]; inpT=[0:512), hT=[512:1536)
#define OFF_CT    98304                // cT [1024][64]
#define OFF_GPART 163840               // [3][4096][64]
#define OFF_QPART 950272               // [4][1024][64]
#define OFF_FM    1212416              // [512]
#define OFF_FL    1212928              // [512]
#define OFF_FACC  1213440              // [512][1024]
#define OFF_XT2   1737728              // [1536][64]
#define OFF_H1P   1836032              // [3][1536][64]
#define OFF_H1T   2130944              // [1536][64]
#define OFF_LOGT  2229248              // [10000][64]
#define OFF_ARGV  2869248              // [1250][64]
#define OFF_ARGI  2949248              // [1250][64] (int)
#define OFF_MASKT 3029248              // [10000][64]
#define OFF_BUF   3669248              // [64][20][512]
#define OFF_BUFT  4324608              // [512][20][64]  bufT[e][t][b]
#define OFF_KVP   4979968              // [64][20][64]
// end: 5061888 floats ~= 20.3 MB

__device__ __forceinline__ float sigmoidf_(float x) { return 1.f / (1.f + expf(-x)); }

// ---------------- init: zero state, transpose h0/c0 into [u][b] layout ----------------
__global__ __launch_bounds__(256) void k_init(const float* __restrict__ h0,
                                              const float* __restrict__ c0,
                                              float* __restrict__ ws) {
  int idx = blockIdx.x * 256 + threadIdx.x, stride = gridDim.x * 256;
  float* inpT = ws + OFF_XT;
  float* hT = ws + OFF_XT + 512 * 64;
  float* cT = ws + OFF_CT;
  float* maskT = ws + OFF_MASKT;
  float* buf = ws + OFF_BUF;
  float* bufT = ws + OFF_BUFT;
  for (int i = idx; i < 512 * 64; i += stride) inpT[i] = 0.f;
  for (int i = idx; i < NV * 64; i += stride) maskT[i] = 0.f;
  for (int i = idx; i < B64 * TT * ED; i += stride) { buf[i] = 0.f; bufT[i] = 0.f; }
  for (int i = idx; i < HD * 64; i += stride) {
    int u = i >> 6, b = i & 63;
    hT[i] = h0[b * HD + u];
    cT[i] = c0[b * HD + u];
  }
}

// ---------------- LSTM gates GEMM: gpart[y][r][b], y = K-split segment ----------------
__global__ __launch_bounds__(256) void k_gates(const float* __restrict__ ws_xt,
                                               const float* __restrict__ w_ih,
                                               const float* __restrict__ w_hh,
                                               float* __restrict__ gpart) {
  int lane = threadIdx.x & 63, wid = threadIdx.x >> 6;
  int r0 = __builtin_amdgcn_readfirstlane((blockIdx.x * 4 + wid) * 8);
  int y = blockIdx.y;
  const float* xT;
  const float* W;
  int ldW;
  if (y == 0) { xT = ws_xt; W = w_ih; ldW = 512; }                    // inp part
  else if (y == 1) { xT = ws_xt + 512 * 64; W = w_hh; ldW = 1024; }   // h[0:512)
  else { xT = ws_xt + 1024 * 64; W = w_hh + 512; ldW = 1024; }        // h[512:1024)
  float acc[8] = {0, 0, 0, 0, 0, 0, 0, 0};
  for (int k = 0; k < 512; ++k) {
    float xv = xT[k * 64 + lane];
#pragma unroll
    for (int i = 0; i < 8; ++i) acc[i] = fmaf(W[(size_t)(r0 + i) * ldW + k], xv, acc[i]);
  }
  float* o = gpart + ((size_t)y * 4096 + r0) * 64 + lane;
#pragma unroll
  for (int i = 0; i < 8; ++i) o[i * 64] = acc[i];
}

// ---------------- LSTM pointwise update (combines gate partials) ----------------
__global__ __launch_bounds__(256) void k_lstm(const float* __restrict__ gpart,
                                              const float* __restrict__ b_ih,
                                              const float* __restrict__ b_hh,
                                              float* __restrict__ cT, float* __restrict__ hT) {
  int i = blockIdx.x * 256 + threadIdx.x;  // 65536
  int u = i >> 6, b = i & 63;
  float g4[4];
#pragma unroll
  for (int gi = 0; gi < 4; ++gi) {
    int r = gi * 1024 + u;
    float v = b_ih[r] + b_hh[r];
#pragma unroll
    for (int y = 0; y < 3; ++y) v += gpart[(size_t)y * 262144 + (size_t)r * 64 + b];
    g4[gi] = v;
  }
  float c = cT[i];
  float cn = sigmoidf_(g4[1]) * c + sigmoidf_(g4[0]) * tanhf(g4[2]);
  float hn = sigmoidf_(g4[3]) * tanhf(cn);
  cT[i] = cn;
  hT[i] = hn;
}

// ---------------- q GEMM (K-split 4) ----------------
__global__ __launch_bounds__(256) void k_q(const float* __restrict__ hT,
                                           const float* __restrict__ w_q,
                                           float* __restrict__ qpart) {
  int lane = threadIdx.x & 63, wid = threadIdx.x >> 6;
  int r0 = __builtin_amdgcn_readfirstlane((blockIdx.x * 4 + wid) * 8);
  int kb = blockIdx.y * 256;
  float acc[8] = {0, 0, 0, 0, 0, 0, 0, 0};
  for (int k = 0; k < 256; ++k) {
    float xv = hT[(kb + k) * 64 + lane];
#pragma unroll
    for (int i = 0; i < 8; ++i) acc[i] = fmaf(w_q[(size_t)(r0 + i) * 1024 + kb + k], xv, acc[i]);
  }
  float* o = qpart + ((size_t)blockIdx.y * 1024 + r0) * 64 + lane;
#pragma unroll
  for (int i = 0; i < 8; ++i) o[i * 64] = acc[i];
}

// ---------------- flash attention over encoder (one pass over enc) ----------------
__global__ __launch_bounds__(256) void k_flash(const float* __restrict__ enc,
                                               const int* __restrict__ tlen,
                                               const float* __restrict__ qpart,
                                               const float* __restrict__ b_q,
                                               float* __restrict__ fm, float* __restrict__ fl,
                                               float* __restrict__ facc) {
  __shared__ float q_lds[1024];
  __shared__ float lacc[4][1024];
  __shared__ float lml[4][2];
  int b = blockIdx.x >> 3, split = blockIdx.x & 7;
  int tid = threadIdx.x, lane = tid & 63, wid = tid >> 6;
  for (int h = tid; h < 1024; h += 256) {
    float v = b_q[h];
#pragma unroll
    for (int ks = 0; ks < 4; ++ks) v += qpart[(size_t)(ks * 1024 + h) * 64 + b];
    q_lds[h] = v;
  }
  __syncthreads();
  int len = tlen[b];
  float qf[16];
#pragma unroll
  for (int j = 0; j < 4; ++j) {
    float4 tq = *(const float4*)&q_lds[j * 256 + lane * 4];
    qf[4 * j + 0] = tq.x; qf[4 * j + 1] = tq.y; qf[4 * j + 2] = tq.z; qf[4 * j + 3] = tq.w;
  }
  float m = -1e30f, l = 0.f, acc[16];
#pragma unroll
  for (int j = 0; j < 16; ++j) acc[j] = 0.f;
  int s0 = split * 64 + wid * 16;
  for (int si = 0; si < 16; ++si) {
    int s = s0 + si;
    if (s >= len) break;  // wave-uniform; s ascending
    const float4* row = (const float4*)(enc + ((size_t)b * SE + s) * HD);
    float4 e4[4];
#pragma unroll
    for (int j = 0; j < 4; ++j) e4[j] = row[j * 64 + lane];
    float d = 0.f;
#pragma unroll
    for (int j = 0; j < 4; ++j) {
      d = fmaf(qf[4 * j + 0], e4[j].x, d);
      d = fmaf(qf[4 * j + 1], e4[j].y, d);
      d = fmaf(qf[4 * j + 2], e4[j].z, d);
      d = fmaf(qf[4 * j + 3], e4[j].w, d);
    }
#pragma unroll
    for (int off = 32; off; off >>= 1) d += __shfl_xor(d, off, 64);
    d = __shfl(d, 0, 64);  // keep all lanes bit-identical
    float mn = fmaxf(m, d);
    float sc = expf(m - mn);
    float p = expf(d - mn);
    l = l * sc + p;
    const float* ef = (const float*)e4;
#pragma unroll
    for (int j = 0; j < 16; ++j) acc[j] = acc[j] * sc + p * ef[j];
    m = mn;
  }
#pragma unroll
  for (int j = 0; j < 4; ++j)
    *(float4*)&lacc[wid][j * 256 + lane * 4] =
        make_float4(acc[4 * j], acc[4 * j + 1], acc[4 * j + 2], acc[4 * j + 3]);
  if (lane == 0) { lml[wid][0] = m; lml[wid][1] = l; }
  __syncthreads();
  float M = fmaxf(fmaxf(lml[0][0], lml[1][0]), fmaxf(lml[2][0], lml[3][0]));
  float w0 = expf(lml[0][0] - M), w1 = expf(lml[1][0] - M);
  float w2 = expf(lml[2][0] - M), w3 = expf(lml[3][0] - M);
  float L = w0 * lml[0][1] + w1 * lml[1][1] + w2 * lml[2][1] + w3 * lml[3][1];
  int p = b * 8 + split;
  for (int h = tid; h < 1024; h += 256)
    facc[(size_t)p * 1024 + h] =
        w0 * lacc[0][h] + w1 * lacc[1][h] + w2 * lacc[2][h] + w3 * lacc[3][h];
  if (tid == 0) { fm[p] = M; fl[p] = L; }
}

// ---------------- combine flash partials; write xT2[0:1024) = sent + attn_enc ----------------
__global__ __launch_bounds__(256) void k_flashcomb(const float* __restrict__ enc,
                                                   const float* __restrict__ fm,
                                                   const float* __restrict__ fl,
                                                   const float* __restrict__ facc,
                                                   float* __restrict__ xT2) {
  int b = blockIdx.x, tid = threadIdx.x;
  float M = -1e30f;
#pragma unroll
  for (int k = 0; k < 8; ++k) M = fmaxf(M, fm[b * 8 + k]);
  float w[8];
  float L = 0.f;
#pragma unroll
  for (int k = 0; k < 8; ++k) {
    w[k] = expf(fm[b * 8 + k] - M);
    L += w[k] * fl[b * 8 + k];
  }
  float inv = 1.f / L;
  for (int h = tid; h < 1024; h += 256) {
    float s = 0.f;
#pragma unroll
    for (int k = 0; k < 8; ++k) s += w[k] * facc[(size_t)(b * 8 + k) * 1024 + h];
    xT2[h * 64 + b] = enc[(size_t)b * SE * HD + h] + s * inv;  // sent = enc[:,0,:]
  }
}

// ---------------- history-attn scores: kvpart[ug][t'][b] ----------------
__global__ __launch_bounds__(256) void k_kv(const float* __restrict__ bufT,
                                            const float* __restrict__ w_k,
                                            const float* __restrict__ b_k,
                                            const float* __restrict__ w_ko,
                                            float* __restrict__ kvpart) {
  int lane = threadIdx.x & 63, wid = threadIdx.x >> 6;
  int ug = blockIdx.x * 4 + wid;  // 0..63
  int u0 = __builtin_amdgcn_readfirstlane(ug * 8);
  int tp = blockIdx.y;  // t'
  const float* xcol = bufT + tp * 64;
  float acc[8] = {0, 0, 0, 0, 0, 0, 0, 0};
  for (int e = 0; e < 512; ++e) {
    float xv = xcol[(size_t)e * (TT * 64) + lane];
#pragma unroll
    for (int i = 0; i < 8; ++i) acc[i] = fmaf(w_k[(size_t)(u0 + i) * 512 + e], xv, acc[i]);
  }
  float kp = 0.f;
#pragma unroll
  for (int i = 0; i < 8; ++i) kp += fmaxf(acc[i] + b_k[u0 + i], 0.f) * w_ko[u0 + i];
  kvpart[((size_t)ug * TT + tp) * 64 + lane] = kp;
}

// ---------------- history-attn finish: softmax over t', xT2[1024:1536) = inp + attn_last ----------------
__global__ __launch_bounds__(256) void k_attn2fin(const float* __restrict__ kvpart,
                                                  const float* __restrict__ b_ko,
                                                  const float* __restrict__ buf,
                                                  const float* __restrict__ inpT,
                                                  float* __restrict__ xT2, int tv) {
  __shared__ float skv[TT];
  int b = blockIdx.x, tid = threadIdx.x;
  if (tid < tv) {
    float s = b_ko[0];
    for (int g = 0; g < 64; ++g) s += kvpart[((size_t)g * TT + tid) * 64 + b];  // ordered: deterministic
    skv[tid] = s;
  }
  __syncthreads();
  float mx = -1e30f;
  for (int k = 0; k < tv; ++k) mx = fmaxf(mx, skv[k]);
  float den = 0.f;
  for (int k = 0; k < tv; ++k) den += expf(skv[k] - mx);
  float inv = 1.f / den;
  for (int e = tid; e < 512; e += 256) {
    float a = 0.f;
    for (int k = 0; k < tv; ++k) a += expf(skv[k] - mx) * inv * buf[((size_t)b * TT + k) * 512 + e];
    xT2[(1024 + e) * 64 + b] = inpT[e * 64 + b] + a;
  }
}

// ---------------- hidden1 GEMM (K-split 3) ----------------
__global__ __launch_bounds__(256) void k_h1(const float* __restrict__ xT2,
                                            const float* __restrict__ w_m1,
                                            float* __restrict__ h1part) {
  int lane = threadIdx.x & 63, wid = threadIdx.x >> 6;
  int r0 = __builtin_amdgcn_readfirstlane((blockIdx.x * 4 + wid) * 8);  // rows 1536
  int kb = blockIdx.y * 512;
  float acc[8] = {0, 0, 0, 0, 0, 0, 0, 0};
  for (int k = 0; k < 512; ++k) {
    float xv = xT2[(kb + k) * 64 + lane];
#pragma unroll
    for (int i = 0; i < 8; ++i) acc[i] = fmaf(w_m1[(size_t)(r0 + i) * MM + kb + k], xv, acc[i]);
  }
  float* o = h1part + ((size_t)blockIdx.y * MM + r0) * 64 + lane;
#pragma unroll
  for (int i = 0; i < 8; ++i) o[i * 64] = acc[i];
}

__global__ __launch_bounds__(256) void k_h1comb(const float* __restrict__ h1part,
                                                const float* __restrict__ b_m1,
                                                float* __restrict__ h1T) {
  int i = blockIdx.x * 256 + threadIdx.x;  // 98304
  int r = i >> 6;
  float v = b_m1[r] + h1part[i] + h1part[98304 + i] + h1part[2 * 98304 + i];
  h1T[i] = fmaxf(v, 0.f);
}

// ---------------- vocab GEMM + mask + per-wavegroup argmax partial ----------------
__global__ __launch_bounds__(256) void k_logits(const float* __restrict__ h1T,
                                                const float* __restrict__ w_m2,
                                                const float* __restrict__ b_m2,
                                                const float* __restrict__ maskT,
                                                float* __restrict__ logT,
                                                float* __restrict__ argv, int* __restrict__ argi) {
  int lane = threadIdx.x & 63, wid = threadIdx.x >> 6;
  int rg = blockIdx.x * 4 + wid;
  if (rg >= 1250) return;
  int r0 = __builtin_amdgcn_readfirstlane(rg * 8);
  float acc[8] = {0, 0, 0, 0, 0, 0, 0, 0};
  for (int k = 0; k < MM; ++k) {
    float xv = h1T[k * 64 + lane];
#pragma unroll
    for (int i = 0; i < 8; ++i) acc[i] = fmaf(w_m2[(size_t)(r0 + i) * MM + k], xv, acc[i]);
  }
  float best = -3.4e38f;
  int bi = 0;
#pragma unroll
  for (int i = 0; i < 8; ++i) {
    int r = r0 + i;
    float v = acc[i] + b_m2[r] + maskT[(size_t)r * 64 + lane];
    logT[(size_t)r * 64 + lane] = v;
    if (v > best) { best = v; bi = r; }  // strict >: first-max wins (matches np.argmax)
  }
  argv[(size_t)rg * 64 + lane] = best;
  argi[(size_t)rg * 64 + lane] = bi;
}

// ---------------- final argmax + feedback (ids, mask, embedding gather, buf update) ----------------
__global__ __launch_bounds__(256) void k_final(const float* __restrict__ argv,
                                               const int* __restrict__ argi,
                                               const float* __restrict__ emb,
                                               float* __restrict__ maskT, float* __restrict__ inpT,
                                               float* __restrict__ buf, float* __restrict__ bufT,
                                               float* __restrict__ out_ids, int t) {
  __shared__ float rv[4][64];
  __shared__ int ri[4][64];
  __shared__ int sid[64];
  int tid = threadIdx.x, lane = tid & 63, wid = tid >> 6;
  int g0 = wid * 313, g1 = min(1250, g0 + 313);
  float best = -3.4e38f;
  int bi = 0;
  for (int g = g0; g < g1; ++g) {
    float v = argv[(size_t)g * 64 + lane];
    if (v > best) { best = v; bi = argi[(size_t)g * 64 + lane]; }
  }
  rv[wid][lane] = best;
  ri[wid][lane] = bi;
  __syncthreads();
  if (tid < 64) {
    float bv = rv[0][tid];
    int bb = ri[0][tid];
#pragma unroll
    for (int w = 1; w < 4; ++w) {
      if (rv[w][tid] > bv) { bv = rv[w][tid]; bb = ri[w][tid]; }
    }
    sid[tid] = bb;
    out_ids[tid * TT + t] = (float)bb;
    if (bb != 1) maskT[(size_t)bb * 64 + tid] = MASK_VALF;  // EOS(1) stays 0
  }
  __syncthreads();
  for (int n = tid; n < 64 * 512; n += 256) {
    int b = n >> 9, e = n & 511;
    float v = emb[(size_t)sid[b] * 512 + e];
    inpT[e * 64 + b] = v;
    buf[((size_t)b * TT + t) * 512 + e] = v;
    bufT[(size_t)e * (TT * 64) + t * 64 + b] = v;
  }
}

// ---------------- transpose logitsT[n][b] -> out[b][t][n] ----------------
__global__ __launch_bounds__(256) void k_lwrite(const float* __restrict__ logT,
                                                float* __restrict__ out, int t) {
  __shared__ float tile[64][65];
  int n0 = blockIdx.x * 64, tid = threadIdx.x;
  for (int idx = tid; idx < 4096; idx += 256) {
    int ni = idx >> 6, b = idx & 63;
    int n = n0 + ni;
    tile[ni][b] = (n < NV) ? logT[(size_t)n * 64 + b] : 0.f;
  }
  __syncthreads();
  for (int idx = tid; idx < 4096; idx += 256) {
    int b = idx >> 6, nj = idx & 63;
    int n = n0 + nj;
    if (n < NV) out[((size_t)b * TT + t) * NV + n] = tile[nj][b];
  }
}

extern "C" void kernel_launch(void* const* d_in, const int* in_sizes, int n_in,
                              void* d_out, int out_size, void* d_ws, size_t ws_size,
                              hipStream_t stream) {
  const float* enc = (const float*)d_in[0];
  const float* h0 = (const float*)d_in[1];
  const float* c0 = (const float*)d_in[2];
  const int* tlen = (const int*)d_in[3];
  // d_in[4] = encoder_mask (recomputed from text_lengths; ignored)
  const float* emb = (const float*)d_in[5];
  const float* w_ih = (const float*)d_in[6];
  const float* w_hh = (const float*)d_in[7];
  const float* b_ih = (const float*)d_in[8];
  const float* b_hh = (const float*)d_in[9];
  const float* w_q = (const float*)d_in[10];
  const float* b_q = (const float*)d_in[11];
  const float* w_k = (const float*)d_in[12];
  const float* b_k = (const float*)d_in[13];
  const float* w_ko = (const float*)d_in[14];
  const float* b_ko = (const float*)d_in[15];
  const float* w_m1 = (const float*)d_in[16];
  const float* b_m1 = (const float*)d_in[17];
  const float* w_m2 = (const float*)d_in[18];
  const float* b_m2 = (const float*)d_in[19];

  float* ws = (float*)d_ws;
  float* out_logits = (float*)d_out;
  float* out_ids = out_logits + (size_t)B64 * TT * NV;

  float* xt = ws + OFF_XT;  // inpT | hT
  float* hT = xt + 512 * 64;

  k_init<<<2048, 256, 0, stream>>>(h0, c0, ws);

  for (int t = 0; t < TT; ++t) {
    int tv = (t < 1) ? 1 : t;
    k_gates<<<dim3(128, 3), 256, 0, stream>>>(xt, w_ih, w_hh, ws + OFF_GPART);
    k_lstm<<<256, 256, 0, stream>>>(ws + OFF_GPART, b_ih, b_hh, ws + OFF_CT, hT);
    k_q<<<dim3(32, 4), 256, 0, stream>>>(hT, w_q, ws + OFF_QPART);
    k_flash<<<512, 256, 0, stream>>>(enc, tlen, ws + OFF_QPART, b_q, ws + OFF_FM, ws + OFF_FL,
                                     ws + OFF_FACC);
    k_flashcomb<<<64, 256, 0, stream>>>(enc, ws + OFF_FM, ws + OFF_FL, ws + OFF_FACC,
                                        ws + OFF_XT2);
    k_kv<<<dim3(16, tv), 256, 0, stream>>>(ws + OFF_BUFT, w_k, b_k, w_ko, ws + OFF_KVP);
    k_attn2fin<<<64, 256, 0, stream>>>(ws + OFF_KVP, b_ko, ws + OFF_BUF, xt, ws + OFF_XT2, tv);
    k_h1<<<dim3(48, 3), 256, 0, stream>>>(ws + OFF_XT2, w_m1, ws + OFF_H1P);
    k_h1comb<<<384, 256, 0, stream>>>(ws + OFF_H1P, b_m1, ws + OFF_H1T);
    k_logits<<<313, 256, 0, stream>>>(ws + OFF_H1T, w_m2, b_m2, ws + OFF_MASKT, ws + OFF_LOGT,
                                      ws + OFF_ARGV, (int*)(ws + OFF_ARGI));
    k_final<<<1, 256, 0, stream>>>(ws + OFF_ARGV, (int*)(ws + OFF_ARGI), emb, ws + OFF_MASKT, xt,
                                   ws + OFF_BUF, ws + OFF_BUFT, out_ids, t);
    k_lwrite<<<157, 256, 0, stream>>>(ws + OFF_LOGT, out_logits, t);
  }
}

// Round 2
// 9494.997 us; speedup vs baseline: 1.3686x; 1.3686x over previous
//
#include <hip/hip_runtime.h>

#define B64 64
#define SE 512
#define HD 1024
#define ED 512
#define NV 10000
#define TT 20
#define MM 1536
#define MASK_VALF -10000000.0f

// ---- workspace offsets (in floats) ----
#define OFF_XT    0                    // xT [1536][64]; inpT=[0:512), hT=[512:1536)
#define OFF_CT    98304                // cT [1024][64]
#define OFF_GPART 163840               // [6][4096][64]
#define OFF_QPART 1736704              // [8][1024][64]
#define OFF_FM    2260992              // [1024]
#define OFF_FL    2262016              // [1024]
#define OFF_FACC  2263040              // [1024][1024]
#define OFF_XT2   3311616              // [1536][64]
#define OFF_H1P   3409920              // [6][1536][64]
#define OFF_H1T   3999744              // [1536][64]
#define OFF_LP    4098048              // [3][10000][64]
#define OFF_LOGT  6018048              // [10000][64]
#define OFF_ARGV  6658048              // [1250][64]
#define OFF_ARGI  6738048              // [1250][64] (int)
#define OFF_MASKT 6818048              // [10000][64]
#define OFF_BUF   7458048              // [64][20][512]
#define OFF_BUFT  8113408              // [512][20][64]  bufT[e][t][b]
#define OFF_KVP   8768768              // [64][20][64]
// end: 8850688 floats ~= 35.4 MB

__device__ __forceinline__ float sigmoidf_(float x) { return 1.f / (1.f + expf(-x)); }

// ---------------- init ----------------
__global__ __launch_bounds__(256) void k_init(const float* __restrict__ h0,
                                              const float* __restrict__ c0,
                                              float* __restrict__ ws) {
  int idx = blockIdx.x * 256 + threadIdx.x, stride = gridDim.x * 256;
  float* inpT = ws + OFF_XT;
  float* hT = ws + OFF_XT + 512 * 64;
  float* cT = ws + OFF_CT;
  float* maskT = ws + OFF_MASKT;
  float* buf = ws + OFF_BUF;
  float* bufT = ws + OFF_BUFT;
  for (int i = idx; i < 512 * 64; i += stride) inpT[i] = 0.f;
  for (int i = idx; i < NV * 64; i += stride) maskT[i] = 0.f;
  for (int i = idx; i < B64 * TT * ED; i += stride) { buf[i] = 0.f; bufT[i] = 0.f; }
  for (int i = idx; i < HD * 64; i += stride) {
    int u = i >> 6, b = i & 63;
    hT[i] = h0[b * HD + u];
    cT[i] = c0[b * HD + u];
  }
}

// ---------------- LSTM gates GEMM: gpart[y][r][b]; y = K-split (6 x 256) ----------------
__global__ __launch_bounds__(256) void k_gates(const float* __restrict__ xt,
                                               const float* __restrict__ w_ih,
                                               const float* __restrict__ w_hh,
                                               float* __restrict__ gpart) {
  int lane = threadIdx.x & 63, wid = threadIdx.x >> 6;
  int r0 = __builtin_amdgcn_readfirstlane((blockIdx.x * 4 + wid) * 8);
  int y = blockIdx.y;
  const float* W;
  int ldW, ko;
  if (y < 2) { W = w_ih; ldW = 512; ko = y * 256; }
  else { W = w_hh; ldW = 1024; ko = (y - 2) * 256; }
  const float* xp = xt + (size_t)(y * 256) * 64 + lane;
  float acc[8] = {0, 0, 0, 0, 0, 0, 0, 0};
  for (int k4 = 0; k4 < 64; ++k4) {
    float x0 = xp[(4 * k4 + 0) * 64];
    float x1 = xp[(4 * k4 + 1) * 64];
    float x2 = xp[(4 * k4 + 2) * 64];
    float x3 = xp[(4 * k4 + 3) * 64];
#pragma unroll
    for (int i = 0; i < 8; ++i) {
      const float4 w4 = *(const float4*)&W[(size_t)(r0 + i) * ldW + ko + 4 * k4];
      acc[i] = fmaf(w4.x, x0, acc[i]);
      acc[i] = fmaf(w4.y, x1, acc[i]);
      acc[i] = fmaf(w4.z, x2, acc[i]);
      acc[i] = fmaf(w4.w, x3, acc[i]);
    }
  }
  float* o = gpart + ((size_t)y * 4096 + r0) * 64 + lane;
#pragma unroll
  for (int i = 0; i < 8; ++i) o[i * 64] = acc[i];
}

// ---------------- LSTM pointwise (combine 6 partials) ----------------
__global__ __launch_bounds__(256) void k_lstm(const float* __restrict__ gpart,
                                              const float* __restrict__ b_ih,
                                              const float* __restrict__ b_hh,
                                              float* __restrict__ cT, float* __restrict__ hT) {
  int i = blockIdx.x * 256 + threadIdx.x;  // 65536
  int u = i >> 6, b = i & 63;
  float g4[4];
#pragma unroll
  for (int gi = 0; gi < 4; ++gi) {
    int r = gi * 1024 + u;
    float v = b_ih[r] + b_hh[r];
#pragma unroll
    for (int y = 0; y < 6; ++y) v += gpart[(size_t)y * 262144 + (size_t)r * 64 + b];
    g4[gi] = v;
  }
  float c = cT[i];
  float cn = sigmoidf_(g4[1]) * c + sigmoidf_(g4[0]) * tanhf(g4[2]);
  float hn = sigmoidf_(g4[3]) * tanhf(cn);
  cT[i] = cn;
  hT[i] = hn;
}

// ---------------- q GEMM (K-split 8 x 128) ----------------
__global__ __launch_bounds__(256) void k_q(const float* __restrict__ hT,
                                           const float* __restrict__ w_q,
                                           float* __restrict__ qpart) {
  int lane = threadIdx.x & 63, wid = threadIdx.x >> 6;
  int r0 = __builtin_amdgcn_readfirstlane((blockIdx.x * 4 + wid) * 8);
  int k0 = blockIdx.y * 128;
  const float* xp = hT + (size_t)k0 * 64 + lane;
  float acc[8] = {0, 0, 0, 0, 0, 0, 0, 0};
  for (int k4 = 0; k4 < 32; ++k4) {
    float x0 = xp[(4 * k4 + 0) * 64];
    float x1 = xp[(4 * k4 + 1) * 64];
    float x2 = xp[(4 * k4 + 2) * 64];
    float x3 = xp[(4 * k4 + 3) * 64];
#pragma unroll
    for (int i = 0; i < 8; ++i) {
      const float4 w4 = *(const float4*)&w_q[(size_t)(r0 + i) * 1024 + k0 + 4 * k4];
      acc[i] = fmaf(w4.x, x0, acc[i]);
      acc[i] = fmaf(w4.y, x1, acc[i]);
      acc[i] = fmaf(w4.z, x2, acc[i]);
      acc[i] = fmaf(w4.w, x3, acc[i]);
    }
  }
  float* o = qpart + ((size_t)blockIdx.y * 1024 + r0) * 64 + lane;
#pragma unroll
  for (int i = 0; i < 8; ++i) o[i * 64] = acc[i];
}

// ---------------- flash attention over encoder (16 s-splits) ----------------
__global__ __launch_bounds__(256) void k_flash(const float* __restrict__ enc,
                                               const int* __restrict__ tlen,
                                               const float* __restrict__ qpart,
                                               const float* __restrict__ b_q,
                                               float* __restrict__ fm, float* __restrict__ fl,
                                               float* __restrict__ facc) {
  __shared__ float q_lds[1024];
  __shared__ float lacc[4][1024];
  __shared__ float lml[4][2];
  int b = blockIdx.x >> 4, split = blockIdx.x & 15;
  int tid = threadIdx.x, lane = tid & 63, wid = tid >> 6;
  for (int h = tid; h < 1024; h += 256) {
    float v = b_q[h];
#pragma unroll
    for (int ks = 0; ks < 8; ++ks) v += qpart[(size_t)(ks * 1024 + h) * 64 + b];
    q_lds[h] = v;
  }
  __syncthreads();
  int len = tlen[b];
  float qf[16];
#pragma unroll
  for (int j = 0; j < 4; ++j) {
    float4 tq = *(const float4*)&q_lds[j * 256 + lane * 4];
    qf[4 * j + 0] = tq.x; qf[4 * j + 1] = tq.y; qf[4 * j + 2] = tq.z; qf[4 * j + 3] = tq.w;
  }
  float m = -1e30f, l = 0.f, acc[16];
#pragma unroll
  for (int j = 0; j < 16; ++j) acc[j] = 0.f;
  int s0 = split * 32 + wid * 8;
  for (int si = 0; si < 8; ++si) {
    int s = s0 + si;
    if (s >= len) break;  // wave-uniform; s ascending
    const float4* row = (const float4*)(enc + ((size_t)b * SE + s) * HD);
    float4 e4[4];
#pragma unroll
    for (int j = 0; j < 4; ++j) e4[j] = row[j * 64 + lane];
    float d = 0.f;
#pragma unroll
    for (int j = 0; j < 4; ++j) {
      d = fmaf(qf[4 * j + 0], e4[j].x, d);
      d = fmaf(qf[4 * j + 1], e4[j].y, d);
      d = fmaf(qf[4 * j + 2], e4[j].z, d);
      d = fmaf(qf[4 * j + 3], e4[j].w, d);
    }
#pragma unroll
    for (int off = 32; off; off >>= 1) d += __shfl_xor(d, off, 64);
    d = __shfl(d, 0, 64);  // all lanes bit-identical
    float mn = fmaxf(m, d);
    float sc = expf(m - mn);
    float p = expf(d - mn);
    l = l * sc + p;
    const float* ef = (const float*)e4;
#pragma unroll
    for (int j = 0; j < 16; ++j) acc[j] = acc[j] * sc + p * ef[j];
    m = mn;
  }
#pragma unroll
  for (int j = 0; j < 4; ++j)
    *(float4*)&lacc[wid][j * 256 + lane * 4] =
        make_float4(acc[4 * j], acc[4 * j + 1], acc[4 * j + 2], acc[4 * j + 3]);
  if (lane == 0) { lml[wid][0] = m; lml[wid][1] = l; }
  __syncthreads();
  float M = fmaxf(fmaxf(lml[0][0], lml[1][0]), fmaxf(lml[2][0], lml[3][0]));
  float w0 = expf(lml[0][0] - M), w1 = expf(lml[1][0] - M);
  float w2 = expf(lml[2][0] - M), w3 = expf(lml[3][0] - M);
  float L = w0 * lml[0][1] + w1 * lml[1][1] + w2 * lml[2][1] + w3 * lml[3][1];
  int p = b * 16 + split;
  for (int h = tid; h < 1024; h += 256)
    facc[(size_t)p * 1024 + h] =
        w0 * lacc[0][h] + w1 * lacc[1][h] + w2 * lacc[2][h] + w3 * lacc[3][h];
  if (tid == 0) { fm[p] = M; fl[p] = L; }
}

// ---------------- combine flash partials; xT2[0:1024) = sent + attn_enc ----------------
__global__ __launch_bounds__(256) void k_flashcomb(const float* __restrict__ enc,
                                                   const float* __restrict__ fm,
                                                   const float* __restrict__ fl,
                                                   const float* __restrict__ facc,
                                                   float* __restrict__ xT2) {
  int b = blockIdx.x, tid = threadIdx.x;
  float M = -1e30f;
#pragma unroll
  for (int k = 0; k < 16; ++k) M = fmaxf(M, fm[b * 16 + k]);
  float w[16];
  float L = 0.f;
#pragma unroll
  for (int k = 0; k < 16; ++k) {
    w[k] = expf(fm[b * 16 + k] - M);
    L += w[k] * fl[b * 16 + k];
  }
  float inv = 1.f / L;
  for (int h = tid; h < 1024; h += 256) {
    float s = 0.f;
#pragma unroll
    for (int k = 0; k < 16; ++k) s += w[k] * facc[(size_t)(b * 16 + k) * 1024 + h];
    xT2[h * 64 + b] = enc[(size_t)b * SE * HD + h] + s * inv;  // sent = enc[:,0,:]
  }
}

// ---------------- incremental history score for buf column j: kvp[ug][j][b] ----------------
__global__ __launch_bounds__(256) void k_knew(const float* __restrict__ bufT,
                                              const float* __restrict__ w_k,
                                              const float* __restrict__ b_k,
                                              const float* __restrict__ w_ko,
                                              float* __restrict__ kvp, int j) {
  int lane = threadIdx.x & 63, wid = threadIdx.x >> 6;
  int ug = blockIdx.x * 4 + wid;  // 0..63
  int u0 = __builtin_amdgcn_readfirstlane(ug * 8);
  const float* xp = bufT + (size_t)j * 64 + lane;  // stride TT*64 per e
  float acc[8] = {0, 0, 0, 0, 0, 0, 0, 0};
  for (int k4 = 0; k4 < 128; ++k4) {
    float x0 = xp[(size_t)(4 * k4 + 0) * (TT * 64)];
    float x1 = xp[(size_t)(4 * k4 + 1) * (TT * 64)];
    float x2 = xp[(size_t)(4 * k4 + 2) * (TT * 64)];
    float x3 = xp[(size_t)(4 * k4 + 3) * (TT * 64)];
#pragma unroll
    for (int i = 0; i < 8; ++i) {
      const float4 w4 = *(const float4*)&w_k[(size_t)(u0 + i) * 512 + 4 * k4];
      acc[i] = fmaf(w4.x, x0, acc[i]);
      acc[i] = fmaf(w4.y, x1, acc[i]);
      acc[i] = fmaf(w4.z, x2, acc[i]);
      acc[i] = fmaf(w4.w, x3, acc[i]);
    }
  }
  float kp = 0.f;
#pragma unroll
  for (int i = 0; i < 8; ++i) kp += fmaxf(acc[i] + b_k[u0 + i], 0.f) * w_ko[u0 + i];
  kvp[((size_t)ug * TT + j) * 64 + lane] = kp;
}

// ---------------- history-attn finish: softmax over t'; xT2[1024:1536) ----------------
__global__ __launch_bounds__(256) void k_attn2fin(const float* __restrict__ kvpart,
                                                  const float* __restrict__ b_ko,
                                                  const float* __restrict__ buf,
                                                  const float* __restrict__ inpT,
                                                  float* __restrict__ xT2, int tv) {
  __shared__ float skv[TT];
  int b = blockIdx.x, tid = threadIdx.x;
  if (tid < tv) {
    float s = b_ko[0];
    for (int g = 0; g < 64; ++g) s += kvpart[((size_t)g * TT + tid) * 64 + b];  // ordered
    skv[tid] = s;
  }
  __syncthreads();
  float mx = -1e30f;
  for (int k = 0; k < tv; ++k) mx = fmaxf(mx, skv[k]);
  float den = 0.f;
  for (int k = 0; k < tv; ++k) den += expf(skv[k] - mx);
  float inv = 1.f / den;
  for (int e = tid; e < 512; e += 256) {
    float a = 0.f;
    for (int k = 0; k < tv; ++k) a += expf(skv[k] - mx) * inv * buf[((size_t)b * TT + k) * 512 + e];
    xT2[(1024 + e) * 64 + b] = inpT[e * 64 + b] + a;
  }
}

// ---------------- hidden1 GEMM (K-split 6 x 256) ----------------
__global__ __launch_bounds__(256) void k_h1(const float* __restrict__ xT2,
                                            const float* __restrict__ w_m1,
                                            float* __restrict__ h1part) {
  int lane = threadIdx.x & 63, wid = threadIdx.x >> 6;
  int r0 = __builtin_amdgcn_readfirstlane((blockIdx.x * 4 + wid) * 8);  // rows 1536
  int k0 = blockIdx.y * 256;
  const float* xp = xT2 + (size_t)k0 * 64 + lane;
  float acc[8] = {0, 0, 0, 0, 0, 0, 0, 0};
  for (int k4 = 0; k4 < 64; ++k4) {
    float x0 = xp[(4 * k4 + 0) * 64];
    float x1 = xp[(4 * k4 + 1) * 64];
    float x2 = xp[(4 * k4 + 2) * 64];
    float x3 = xp[(4 * k4 + 3) * 64];
#pragma unroll
    for (int i = 0; i < 8; ++i) {
      const float4 w4 = *(const float4*)&w_m1[(size_t)(r0 + i) * MM + k0 + 4 * k4];
      acc[i] = fmaf(w4.x, x0, acc[i]);
      acc[i] = fmaf(w4.y, x1, acc[i]);
      acc[i] = fmaf(w4.z, x2, acc[i]);
      acc[i] = fmaf(w4.w, x3, acc[i]);
    }
  }
  float* o = h1part + ((size_t)blockIdx.y * MM + r0) * 64 + lane;
#pragma unroll
  for (int i = 0; i < 8; ++i) o[i * 64] = acc[i];
}

__global__ __launch_bounds__(256) void k_h1comb(const float* __restrict__ h1part,
                                                const float* __restrict__ b_m1,
                                                float* __restrict__ h1T) {
  int i = blockIdx.x * 256 + threadIdx.x;  // 98304
  int r = i >> 6;
  float v = b_m1[r];
#pragma unroll
  for (int s = 0; s < 6; ++s) v += h1part[(size_t)s * 98304 + i];
  h1T[i] = fmaxf(v, 0.f);
}

// ---------------- vocab GEMM partials (K-split 3 x 512) ----------------
__global__ __launch_bounds__(256) void k_glog(const float* __restrict__ h1T,
                                              const float* __restrict__ w_m2,
                                              float* __restrict__ lp) {
  int lane = threadIdx.x & 63, wid = threadIdx.x >> 6;
  int rg = blockIdx.x * 4 + wid;
  if (rg >= 1250) return;
  int r0 = __builtin_amdgcn_readfirstlane(rg * 8);
  int k0 = blockIdx.y * 512;
  const float* xp = h1T + (size_t)k0 * 64 + lane;
  float acc[8] = {0, 0, 0, 0, 0, 0, 0, 0};
  for (int k4 = 0; k4 < 128; ++k4) {
    float x0 = xp[(4 * k4 + 0) * 64];
    float x1 = xp[(4 * k4 + 1) * 64];
    float x2 = xp[(4 * k4 + 2) * 64];
    float x3 = xp[(4 * k4 + 3) * 64];
#pragma unroll
    for (int i = 0; i < 8; ++i) {
      const float4 w4 = *(const float4*)&w_m2[(size_t)(r0 + i) * MM + k0 + 4 * k4];
      acc[i] = fmaf(w4.x, x0, acc[i]);
      acc[i] = fmaf(w4.y, x1, acc[i]);
      acc[i] = fmaf(w4.z, x2, acc[i]);
      acc[i] = fmaf(w4.w, x3, acc[i]);
    }
  }
  float* o = lp + (size_t)blockIdx.y * 640000 + (size_t)r0 * 64 + lane;
#pragma unroll
  for (int i = 0; i < 8; ++i) o[i * 64] = acc[i];
}

// ---------------- logits finish: combine + bias + mask + argmax partials ----------------
__global__ __launch_bounds__(256) void k_logfin(const float* __restrict__ lp,
                                                const float* __restrict__ b_m2,
                                                const float* __restrict__ maskT,
                                                float* __restrict__ logT,
                                                float* __restrict__ argv, int* __restrict__ argi) {
  int lane = threadIdx.x & 63, wid = threadIdx.x >> 6;
  int rg = blockIdx.x * 4 + wid;
  if (rg >= 1250) return;
  int r0 = rg * 8;
  float best = -3.4e38f;
  int bi = 0;
#pragma unroll
  for (int i = 0; i < 8; ++i) {
    int r = r0 + i;
    size_t idx = (size_t)r * 64 + lane;
    float v = lp[idx] + lp[640000 + idx] + lp[2 * 640000 + idx] + b_m2[r] + maskT[idx];
    logT[idx] = v;
    if (v > best) { best = v; bi = r; }  // strict >: first-max wins
  }
  argv[(size_t)rg * 64 + lane] = best;
  argi[(size_t)rg * 64 + lane] = bi;
}

// ---------------- final argmax + feedback ----------------
__global__ __launch_bounds__(256) void k_final(const float* __restrict__ argv,
                                               const int* __restrict__ argi,
                                               const float* __restrict__ emb,
                                               float* __restrict__ maskT, float* __restrict__ inpT,
                                               float* __restrict__ buf, float* __restrict__ bufT,
                                               float* __restrict__ out_ids, int t) {
  __shared__ float rv[4][64];
  __shared__ int ri[4][64];
  __shared__ int sid[64];
  int tid = threadIdx.x, lane = tid & 63, wid = tid >> 6;
  int g0 = wid * 313, g1 = min(1250, g0 + 313);
  float best = -3.4e38f;
  int bi = 0;
  for (int g = g0; g < g1; ++g) {
    float v = argv[(size_t)g * 64 + lane];
    if (v > best) { best = v; bi = argi[(size_t)g * 64 + lane]; }
  }
  rv[wid][lane] = best;
  ri[wid][lane] = bi;
  __syncthreads();
  if (tid < 64) {
    float bv = rv[0][tid];
    int bb = ri[0][tid];
#pragma unroll
    for (int w = 1; w < 4; ++w) {
      if (rv[w][tid] > bv) { bv = rv[w][tid]; bb = ri[w][tid]; }
    }
    sid[tid] = bb;
    out_ids[tid * TT + t] = (float)bb;
    if (bb != 1) maskT[(size_t)bb * 64 + tid] = MASK_VALF;  // EOS(1) stays 0
  }
  __syncthreads();
  for (int n = tid; n < 64 * 512; n += 256) {
    int b = n >> 9, e = n & 511;
    float v = emb[(size_t)sid[b] * 512 + e];
    inpT[e * 64 + b] = v;
    buf[((size_t)b * TT + t) * 512 + e] = v;
    bufT[(size_t)e * (TT * 64) + t * 64 + b] = v;
  }
}

// ---------------- transpose logitsT[n][b] -> out[b][t][n] ----------------
__global__ __launch_bounds__(256) void k_lwrite(const float* __restrict__ logT,
                                                float* __restrict__ out, int t) {
  __shared__ float tile[64][65];
  int n0 = blockIdx.x * 64, tid = threadIdx.x;
  for (int idx = tid; idx < 4096; idx += 256) {
    int ni = idx >> 6, b = idx & 63;
    int n = n0 + ni;
    tile[ni][b] = (n < NV) ? logT[(size_t)n * 64 + b] : 0.f;
  }
  __syncthreads();
  for (int idx = tid; idx < 4096; idx += 256) {
    int b = idx >> 6, nj = idx & 63;
    int n = n0 + nj;
    if (n < NV) out[((size_t)b * TT + t) * NV + n] = tile[nj][b];
  }
}

extern "C" void kernel_launch(void* const* d_in, const int* in_sizes, int n_in,
                              void* d_out, int out_size, void* d_ws, size_t ws_size,
                              hipStream_t stream) {
  const float* enc = (const float*)d_in[0];
  const float* h0 = (const float*)d_in[1];
  const float* c0 = (const float*)d_in[2];
  const int* tlen = (const int*)d_in[3];
  const float* emb = (const float*)d_in[5];
  const float* w_ih = (const float*)d_in[6];
  const float* w_hh = (const float*)d_in[7];
  const float* b_ih = (const float*)d_in[8];
  const float* b_hh = (const float*)d_in[9];
  const float* w_q = (const float*)d_in[10];
  const float* b_q = (const float*)d_in[11];
  const float* w_k = (const float*)d_in[12];
  const float* b_k = (const float*)d_in[13];
  const float* w_ko = (const float*)d_in[14];
  const float* b_ko = (const float*)d_in[15];
  const float* w_m1 = (const float*)d_in[16];
  const float* b_m1 = (const float*)d_in[17];
  const float* w_m2 = (const float*)d_in[18];
  const float* b_m2 = (const float*)d_in[19];

  float* ws = (float*)d_ws;
  float* out_logits = (float*)d_out;
  float* out_ids = out_logits + (size_t)B64 * TT * NV;

  float* xt = ws + OFF_XT;  // inpT | hT
  float* hT = xt + 512 * 64;

  k_init<<<2048, 256, 0, stream>>>(h0, c0, ws);
  k_knew<<<16, 256, 0, stream>>>(ws + OFF_BUFT, w_k, b_k, w_ko, ws + OFF_KVP, 0);  // zero-row score

  for (int t = 0; t < TT; ++t) {
    int tv = (t < 1) ? 1 : t;
    k_gates<<<dim3(128, 6), 256, 0, stream>>>(xt, w_ih, w_hh, ws + OFF_GPART);
    k_lstm<<<256, 256, 0, stream>>>(ws + OFF_GPART, b_ih, b_hh, ws + OFF_CT, hT);
    k_q<<<dim3(32, 8), 256, 0, stream>>>(hT, w_q, ws + OFF_QPART);
    k_flash<<<1024, 256, 0, stream>>>(enc, tlen, ws + OFF_QPART, b_q, ws + OFF_FM, ws + OFF_FL,
                                      ws + OFF_FACC);
    k_flashcomb<<<64, 256, 0, stream>>>(enc, ws + OFF_FM, ws + OFF_FL, ws + OFF_FACC,
                                        ws + OFF_XT2);
    k_attn2fin<<<64, 256, 0, stream>>>(ws + OFF_KVP, b_ko, ws + OFF_BUF, xt, ws + OFF_XT2, tv);
    k_h1<<<dim3(48, 6), 256, 0, stream>>>(ws + OFF_XT2, w_m1, ws + OFF_H1P);
    k_h1comb<<<384, 256, 0, stream>>>(ws + OFF_H1P, b_m1, ws + OFF_H1T);
    k_glog<<<dim3(313, 3), 256, 0, stream>>>(ws + OFF_H1T, w_m2, ws + OFF_LP);
    k_logfin<<<313, 256, 0, stream>>>(ws + OFF_LP, b_m2, ws + OFF_MASKT, ws + OFF_LOGT,
                                      ws + OFF_ARGV, (int*)(ws + OFF_ARGI));
    k_final<<<1, 256, 0, stream>>>(ws + OFF_ARGV, (int*)(ws + OFF_ARGI), emb, ws + OFF_MASKT, xt,
                                   ws + OFF_BUF, ws + OFF_BUFT, out_ids, t);
    if (t < TT - 1)
      k_knew<<<16, 256, 0, stream>>>(ws + OFF_BUFT, w_k, b_k, w_ko, ws + OFF_KVP, t);
    k_lwrite<<<157, 256, 0, stream>>>(ws + OFF_LOGT, out_logits, t);
  }
}

// Round 3
// 4340.075 us; speedup vs baseline: 2.9942x; 2.1877x over previous
//
#include <hip/hip_runtime.h>

#define B64 64
#define SE 512
#define HD 1024
#define ED 512
#define NV 10000
#define TT 20
#define MM 1536
#define MASK_VALF -10000000.0f

// ---- workspace offsets (floats); regions time-shared within a step ----
#define OFF_XT    0                    // xT [1536][64]; inpT=[0:512), hT=[512:1536)
#define OFF_CT    98304                // cT [1024][64]
#define OFF_A     163840               // REGION A (3,840,000): GPART[12][4096][64] | H1P[12][1536][64] | LP[6][10000][64]
#define OFF_B     4003840              // REGION B (1,048,576): QPART[16][1024][64] | FACC[1024][1024]
#define OFF_QF    5052416              // qf [64][1024]
#define OFF_FM    5117952              // [1024]
#define OFF_FL    5118976              // [1024]
#define OFF_XT2   5120000              // [1536][64]
#define OFF_H1T   5218304              // [1536][64]
#define OFF_ARGV  5316608              // [1250][64]
#define OFF_ARGI  5396608              // [1250][64] (int)
#define OFF_MASKT 5476608              // [10000][64]
#define OFF_BUF   6116608              // [64][20][512]
#define OFF_BUFT  6771968              // [512][20][64]
#define OFF_KVP   7427328              // [64][20][64]
// end: 7509248 floats ~= 30.0 MB

__device__ __forceinline__ float sigmoidf_(float x) { return 1.f / (1.f + expf(-x)); }

// ---------------- init ----------------
__global__ __launch_bounds__(256) void k_init(const float* __restrict__ h0,
                                              const float* __restrict__ c0,
                                              float* __restrict__ ws) {
  int idx = blockIdx.x * 256 + threadIdx.x, stride = gridDim.x * 256;
  float* inpT = ws + OFF_XT;
  float* hT = ws + OFF_XT + 512 * 64;
  float* cT = ws + OFF_CT;
  float* maskT = ws + OFF_MASKT;
  float* buf = ws + OFF_BUF;
  float* bufT = ws + OFF_BUFT;
  for (int i = idx; i < 512 * 64; i += stride) inpT[i] = 0.f;
  for (int i = idx; i < NV * 64; i += stride) maskT[i] = 0.f;
  for (int i = idx; i < B64 * TT * ED; i += stride) { buf[i] = 0.f; bufT[i] = 0.f; }
  for (int i = idx; i < HD * 64; i += stride) {
    int u = i >> 6, b = i & 63;
    hT[i] = h0[b * HD + u];
    cT[i] = c0[b * HD + u];
  }
}

// ---------------- LSTM gates GEMM: 12 K-splits of 128 ----------------
__global__ __launch_bounds__(256) void k_gates(const float* __restrict__ xt,
                                               const float* __restrict__ w_ih,
                                               const float* __restrict__ w_hh,
                                               float* __restrict__ gpart) {
  int lane = threadIdx.x & 63, wid = threadIdx.x >> 6;
  int r0 = __builtin_amdgcn_readfirstlane((blockIdx.x * 4 + wid) * 8);
  int y = blockIdx.y;  // 0..11
  const float* W;
  int ldW, ko, xo;
  if (y < 4) { W = w_ih; ldW = 512; ko = y * 128; xo = ko; }
  else { W = w_hh; ldW = 1024; ko = (y - 4) * 128; xo = 512 + ko; }
  const float* xp = xt + (size_t)xo * 64 + lane;
  float acc[8] = {0, 0, 0, 0, 0, 0, 0, 0};
  for (int k4 = 0; k4 < 32; ++k4) {
    float x0 = xp[(4 * k4 + 0) * 64];
    float x1 = xp[(4 * k4 + 1) * 64];
    float x2 = xp[(4 * k4 + 2) * 64];
    float x3 = xp[(4 * k4 + 3) * 64];
#pragma unroll
    for (int i = 0; i < 8; ++i) {
      const float4 w4 = *(const float4*)&W[(size_t)(r0 + i) * ldW + ko + 4 * k4];
      acc[i] = fmaf(w4.x, x0, acc[i]);
      acc[i] = fmaf(w4.y, x1, acc[i]);
      acc[i] = fmaf(w4.z, x2, acc[i]);
      acc[i] = fmaf(w4.w, x3, acc[i]);
    }
  }
  float* o = gpart + ((size_t)y * 4096 + r0) * 64 + lane;
#pragma unroll
  for (int i = 0; i < 8; ++i) o[i * 64] = acc[i];
}

// ---------------- LSTM pointwise (combine 12 partials) ----------------
__global__ __launch_bounds__(256) void k_lstm(const float* __restrict__ gpart,
                                              const float* __restrict__ b_ih,
                                              const float* __restrict__ b_hh,
                                              float* __restrict__ cT, float* __restrict__ hT) {
  int i = blockIdx.x * 256 + threadIdx.x;  // 65536
  int u = i >> 6, b = i & 63;
  float g4[4];
#pragma unroll
  for (int gi = 0; gi < 4; ++gi) {
    int r = gi * 1024 + u;
    float v = b_ih[r] + b_hh[r];
#pragma unroll
    for (int y = 0; y < 12; ++y) v += gpart[(size_t)y * 262144 + (size_t)r * 64 + b];
    g4[gi] = v;
  }
  float c = cT[i];
  float cn = sigmoidf_(g4[1]) * c + sigmoidf_(g4[0]) * tanhf(g4[2]);
  float hn = sigmoidf_(g4[3]) * tanhf(cn);
  cT[i] = cn;
  hT[i] = hn;
}

// ---------------- q GEMM (16 K-splits of 64) ----------------
__global__ __launch_bounds__(256) void k_q(const float* __restrict__ hT,
                                           const float* __restrict__ w_q,
                                           float* __restrict__ qpart) {
  int lane = threadIdx.x & 63, wid = threadIdx.x >> 6;
  int r0 = __builtin_amdgcn_readfirstlane((blockIdx.x * 4 + wid) * 8);
  int k0 = blockIdx.y * 64;
  const float* xp = hT + (size_t)k0 * 64 + lane;
  float acc[8] = {0, 0, 0, 0, 0, 0, 0, 0};
  for (int k4 = 0; k4 < 16; ++k4) {
    float x0 = xp[(4 * k4 + 0) * 64];
    float x1 = xp[(4 * k4 + 1) * 64];
    float x2 = xp[(4 * k4 + 2) * 64];
    float x3 = xp[(4 * k4 + 3) * 64];
#pragma unroll
    for (int i = 0; i < 8; ++i) {
      const float4 w4 = *(const float4*)&w_q[(size_t)(r0 + i) * 1024 + k0 + 4 * k4];
      acc[i] = fmaf(w4.x, x0, acc[i]);
      acc[i] = fmaf(w4.y, x1, acc[i]);
      acc[i] = fmaf(w4.z, x2, acc[i]);
      acc[i] = fmaf(w4.w, x3, acc[i]);
    }
  }
  float* o = qpart + ((size_t)blockIdx.y * 1024 + r0) * 64 + lane;
#pragma unroll
  for (int i = 0; i < 8; ++i) o[i * 64] = acc[i];
}

// ---------------- combine q splits + b_q -> qf[b][h] (transposed via LDS) ----------------
__global__ __launch_bounds__(256) void k_qfin(const float* __restrict__ qpart,
                                              const float* __restrict__ b_q,
                                              float* __restrict__ qf) {
  __shared__ float tile[64][65];
  int h0 = blockIdx.x * 64;
  int lane = threadIdx.x & 63, hrow = threadIdx.x >> 6;
#pragma unroll
  for (int p = 0; p < 16; ++p) {
    int hl = p * 4 + hrow;
    int h = h0 + hl;
    float v = b_q[h];
#pragma unroll
    for (int s = 0; s < 16; ++s) v += qpart[((size_t)s * 1024 + h) * 64 + lane];
    tile[hl][lane] = v;
  }
  __syncthreads();
#pragma unroll
  for (int p = 0; p < 16; ++p) {
    int b = p * 4 + hrow;
    qf[(size_t)b * 1024 + h0 + lane] = tile[lane][b];
  }
}

// ---------------- flash attention: pair-processed, software-pipelined ----------------
__global__ __launch_bounds__(256) void k_flash(const float* __restrict__ enc,
                                               const int* __restrict__ tlen,
                                               const float* __restrict__ qf,
                                               float* __restrict__ fm, float* __restrict__ fl,
                                               float* __restrict__ facc) {
  __shared__ float lacc[4][1024];
  __shared__ float lml[4][2];
  int b = blockIdx.x >> 4, split = blockIdx.x & 15;
  int tid = threadIdx.x, lane = tid & 63, wid = tid >> 6;
  int len = tlen[b];
  float qv[16];
#pragma unroll
  for (int j = 0; j < 4; ++j) {
    float4 tq = *(const float4*)&qf[(size_t)b * 1024 + j * 256 + lane * 4];
    qv[4 * j + 0] = tq.x; qv[4 * j + 1] = tq.y; qv[4 * j + 2] = tq.z; qv[4 * j + 3] = tq.w;
  }
  const float* base = enc + (size_t)b * SE * HD;
  int s0 = split * 32 + wid * 8;
  int nr = len - s0;
  nr = nr < 0 ? 0 : (nr > 8 ? 8 : nr);
  int npair = nr >> 1;

  float4 cA[4], cB[4], nA[4], nB[4];
  float m = -1e30f, l = 0.f, acc[16];
#pragma unroll
  for (int j = 0; j < 16; ++j) acc[j] = 0.f;

#define LOADROW(d, s)                                            \
  {                                                              \
    const float4* rp = (const float4*)(base + (size_t)(s)*HD) + lane; \
    d[0] = rp[0]; d[1] = rp[64]; d[2] = rp[128]; d[3] = rp[192]; \
  }

  if (npair > 0) { LOADROW(cA, s0); LOADROW(cB, s0 + 1); }
  for (int p = 0; p < npair; ++p) {
    if (p + 1 < npair) {
      LOADROW(nA, s0 + 2 * p + 2);
      LOADROW(nB, s0 + 2 * p + 3);
    } else if (nr & 1) {
      LOADROW(nA, s0 + nr - 1);
    }
    float d0 = 0.f, d1 = 0.f;
#pragma unroll
    for (int j = 0; j < 4; ++j) {
      d0 = fmaf(qv[4 * j + 0], cA[j].x, d0); d1 = fmaf(qv[4 * j + 0], cB[j].x, d1);
      d0 = fmaf(qv[4 * j + 1], cA[j].y, d0); d1 = fmaf(qv[4 * j + 1], cB[j].y, d1);
      d0 = fmaf(qv[4 * j + 2], cA[j].z, d0); d1 = fmaf(qv[4 * j + 2], cB[j].z, d1);
      d0 = fmaf(qv[4 * j + 3], cA[j].w, d0); d1 = fmaf(qv[4 * j + 3], cB[j].w, d1);
    }
#pragma unroll
    for (int off = 32; off; off >>= 1) { d0 += __shfl_xor(d0, off, 64); d1 += __shfl_xor(d1, off, 64); }
    d0 = __shfl(d0, 0, 64);
    d1 = __shfl(d1, 0, 64);
    float mn = fmaxf(m, fmaxf(d0, d1));
    float sc = expf(m - mn), p0 = expf(d0 - mn), p1 = expf(d1 - mn);
    l = l * sc + p0 + p1;
#pragma unroll
    for (int j = 0; j < 4; ++j) {
      acc[4 * j + 0] = fmaf(p1, cB[j].x, fmaf(p0, cA[j].x, acc[4 * j + 0] * sc));
      acc[4 * j + 1] = fmaf(p1, cB[j].y, fmaf(p0, cA[j].y, acc[4 * j + 1] * sc));
      acc[4 * j + 2] = fmaf(p1, cB[j].z, fmaf(p0, cA[j].z, acc[4 * j + 2] * sc));
      acc[4 * j + 3] = fmaf(p1, cB[j].w, fmaf(p0, cA[j].w, acc[4 * j + 3] * sc));
    }
    m = mn;
#pragma unroll
    for (int j = 0; j < 4; ++j) { cA[j] = nA[j]; cB[j] = nB[j]; }
  }
  if (nr & 1) {
    if (npair == 0) LOADROW(cA, s0);
    float d0 = 0.f;
#pragma unroll
    for (int j = 0; j < 4; ++j) {
      d0 = fmaf(qv[4 * j + 0], cA[j].x, d0);
      d0 = fmaf(qv[4 * j + 1], cA[j].y, d0);
      d0 = fmaf(qv[4 * j + 2], cA[j].z, d0);
      d0 = fmaf(qv[4 * j + 3], cA[j].w, d0);
    }
#pragma unroll
    for (int off = 32; off; off >>= 1) d0 += __shfl_xor(d0, off, 64);
    d0 = __shfl(d0, 0, 64);
    float mn = fmaxf(m, d0);
    float sc = expf(m - mn), p0 = expf(d0 - mn);
    l = l * sc + p0;
#pragma unroll
    for (int j = 0; j < 4; ++j) {
      acc[4 * j + 0] = fmaf(p0, cA[j].x, acc[4 * j + 0] * sc);
      acc[4 * j + 1] = fmaf(p0, cA[j].y, acc[4 * j + 1] * sc);
      acc[4 * j + 2] = fmaf(p0, cA[j].z, acc[4 * j + 2] * sc);
      acc[4 * j + 3] = fmaf(p0, cA[j].w, acc[4 * j + 3] * sc);
    }
    m = mn;
  }
#undef LOADROW
#pragma unroll
  for (int j = 0; j < 4; ++j)
    *(float4*)&lacc[wid][j * 256 + lane * 4] =
        make_float4(acc[4 * j], acc[4 * j + 1], acc[4 * j + 2], acc[4 * j + 3]);
  if (lane == 0) { lml[wid][0] = m; lml[wid][1] = l; }
  __syncthreads();
  float M = fmaxf(fmaxf(lml[0][0], lml[1][0]), fmaxf(lml[2][0], lml[3][0]));
  float w0 = expf(lml[0][0] - M), w1 = expf(lml[1][0] - M);
  float w2 = expf(lml[2][0] - M), w3 = expf(lml[3][0] - M);
  float L = w0 * lml[0][1] + w1 * lml[1][1] + w2 * lml[2][1] + w3 * lml[3][1];
  int p = b * 16 + split;
  for (int h = tid; h < 1024; h += 256)
    facc[(size_t)p * 1024 + h] =
        w0 * lacc[0][h] + w1 * lacc[1][h] + w2 * lacc[2][h] + w3 * lacc[3][h];
  if (tid == 0) { fm[p] = M; fl[p] = L; }
}

// ---------------- fused: flash combine + history softmax -> full xT2 ----------------
__global__ __launch_bounds__(256) void k_ctx(const float* __restrict__ enc,
                                             const float* __restrict__ fm,
                                             const float* __restrict__ fl,
                                             const float* __restrict__ facc,
                                             const float* __restrict__ kvp,
                                             const float* __restrict__ b_ko,
                                             const float* __restrict__ buf,
                                             const float* __restrict__ inpT,
                                             float* __restrict__ xT2, int tv) {
  __shared__ float pw[TT];
  int b = blockIdx.x, tid = threadIdx.x;
  // history scores (64 ordered partial groups)
  if (tid < tv) {
    float s = b_ko[0];
    for (int g = 0; g < 64; ++g) s += kvp[((size_t)g * TT + tid) * 64 + b];
    pw[tid] = s;
  }
  __syncthreads();
  float mx = -1e30f;
  for (int k = 0; k < tv; ++k) mx = fmaxf(mx, pw[k]);
  float den = 0.f;
  for (int k = 0; k < tv; ++k) den += expf(pw[k] - mx);
  float invd = 1.f / den;
  __syncthreads();
  if (tid < tv) pw[tid] = expf(pw[tid] - mx) * invd;
  __syncthreads();
  // flash combine
  float M = -1e30f;
#pragma unroll
  for (int k = 0; k < 16; ++k) M = fmaxf(M, fm[b * 16 + k]);
  float w[16];
  float L = 0.f;
#pragma unroll
  for (int k = 0; k < 16; ++k) {
    w[k] = expf(fm[b * 16 + k] - M);
    L += w[k] * fl[b * 16 + k];
  }
  float inv = 1.f / L;
  for (int h = tid; h < 1024; h += 256) {
    float s = 0.f;
#pragma unroll
    for (int k = 0; k < 16; ++k) s += w[k] * facc[(size_t)(b * 16 + k) * 1024 + h];
    xT2[h * 64 + b] = enc[(size_t)b * SE * HD + h] + s * inv;
  }
  // history weighted sum
  for (int e = tid; e < 512; e += 256) {
    float a = 0.f;
    for (int k = 0; k < tv; ++k) a += pw[k] * buf[((size_t)b * TT + k) * 512 + e];
    xT2[(1024 + e) * 64 + b] = inpT[e * 64 + b] + a;
  }
}

// ---------------- incremental history score for buf column j ----------------
__global__ __launch_bounds__(256) void k_kscore(const float* __restrict__ bufT,
                                                const float* __restrict__ w_k,
                                                const float* __restrict__ b_k,
                                                const float* __restrict__ w_ko,
                                                float* __restrict__ kvp, int j) {
  __shared__ float sacc[4][8][64];
  int lane = threadIdx.x & 63, wid = threadIdx.x >> 6;
  int ug = blockIdx.x;  // 0..63
  int u0 = ug * 8;
  int k0 = wid * 128;
  const float* xp = bufT + (size_t)j * 64 + lane;
  float acc[8] = {0, 0, 0, 0, 0, 0, 0, 0};
  for (int k4 = 0; k4 < 32; ++k4) {
    int e = k0 + 4 * k4;
    float x0 = xp[(size_t)(e + 0) * (TT * 64)];
    float x1 = xp[(size_t)(e + 1) * (TT * 64)];
    float x2 = xp[(size_t)(e + 2) * (TT * 64)];
    float x3 = xp[(size_t)(e + 3) * (TT * 64)];
#pragma unroll
    for (int i = 0; i < 8; ++i) {
      const float4 w4 = *(const float4*)&w_k[(size_t)(u0 + i) * 512 + e];
      acc[i] = fmaf(w4.x, x0, acc[i]);
      acc[i] = fmaf(w4.y, x1, acc[i]);
      acc[i] = fmaf(w4.z, x2, acc[i]);
      acc[i] = fmaf(w4.w, x3, acc[i]);
    }
  }
#pragma unroll
  for (int i = 0; i < 8; ++i) sacc[wid][i][lane] = acc[i];
  __syncthreads();
  if (wid == 0) {
    float kp = 0.f;
#pragma unroll
    for (int i = 0; i < 8; ++i) {
      float tot = b_k[u0 + i] + sacc[0][i][lane] + sacc[1][i][lane] + sacc[2][i][lane] +
                  sacc[3][i][lane];
      kp += fmaxf(tot, 0.f) * w_ko[u0 + i];
    }
    kvp[((size_t)ug * TT + j) * 64 + lane] = kp;
  }
}

// ---------------- hidden1 GEMM (12 K-splits of 128) ----------------
__global__ __launch_bounds__(256) void k_h1(const float* __restrict__ xT2,
                                            const float* __restrict__ w_m1,
                                            float* __restrict__ h1part) {
  int lane = threadIdx.x & 63, wid = threadIdx.x >> 6;
  int r0 = __builtin_amdgcn_readfirstlane((blockIdx.x * 4 + wid) * 8);
  int k0 = blockIdx.y * 128;
  const float* xp = xT2 + (size_t)k0 * 64 + lane;
  float acc[8] = {0, 0, 0, 0, 0, 0, 0, 0};
  for (int k4 = 0; k4 < 32; ++k4) {
    float x0 = xp[(4 * k4 + 0) * 64];
    float x1 = xp[(4 * k4 + 1) * 64];
    float x2 = xp[(4 * k4 + 2) * 64];
    float x3 = xp[(4 * k4 + 3) * 64];
#pragma unroll
    for (int i = 0; i < 8; ++i) {
      const float4 w4 = *(const float4*)&w_m1[(size_t)(r0 + i) * MM + k0 + 4 * k4];
      acc[i] = fmaf(w4.x, x0, acc[i]);
      acc[i] = fmaf(w4.y, x1, acc[i]);
      acc[i] = fmaf(w4.z, x2, acc[i]);
      acc[i] = fmaf(w4.w, x3, acc[i]);
    }
  }
  float* o = h1part + ((size_t)blockIdx.y * MM + r0) * 64 + lane;
#pragma unroll
  for (int i = 0; i < 8; ++i) o[i * 64] = acc[i];
}

__global__ __launch_bounds__(256) void k_h1comb(const float* __restrict__ h1part,
                                                const float* __restrict__ b_m1,
                                                float* __restrict__ h1T) {
  int i = blockIdx.x * 256 + threadIdx.x;  // 98304
  int r = i >> 6;
  float v = b_m1[r];
#pragma unroll
  for (int s = 0; s < 12; ++s) v += h1part[(size_t)s * 98304 + i];
  h1T[i] = fmaxf(v, 0.f);
}

// ---------------- vocab GEMM partials (6 K-splits of 256) ----------------
__global__ __launch_bounds__(256) void k_glog(const float* __restrict__ h1T,
                                              const float* __restrict__ w_m2,
                                              float* __restrict__ lp) {
  int lane = threadIdx.x & 63, wid = threadIdx.x >> 6;
  int rg = blockIdx.x * 4 + wid;
  if (rg >= 1250) return;
  int r0 = __builtin_amdgcn_readfirstlane(rg * 8);
  int k0 = blockIdx.y * 256;
  const float* xp = h1T + (size_t)k0 * 64 + lane;
  float acc[8] = {0, 0, 0, 0, 0, 0, 0, 0};
  for (int k4 = 0; k4 < 64; ++k4) {
    float x0 = xp[(4 * k4 + 0) * 64];
    float x1 = xp[(4 * k4 + 1) * 64];
    float x2 = xp[(4 * k4 + 2) * 64];
    float x3 = xp[(4 * k4 + 3) * 64];
#pragma unroll
    for (int i = 0; i < 8; ++i) {
      const float4 w4 = *(const float4*)&w_m2[(size_t)(r0 + i) * MM + k0 + 4 * k4];
      acc[i] = fmaf(w4.x, x0, acc[i]);
      acc[i] = fmaf(w4.y, x1, acc[i]);
      acc[i] = fmaf(w4.z, x2, acc[i]);
      acc[i] = fmaf(w4.w, x3, acc[i]);
    }
  }
  float* o = lp + (size_t)blockIdx.y * 640000 + (size_t)r0 * 64 + lane;
#pragma unroll
  for (int i = 0; i < 8; ++i) o[i * 64] = acc[i];
}

// ---------------- logits finish: combine + bias + mask + argmax + transposed out-write ----------------
__global__ __launch_bounds__(256) void k_logfin(const float* __restrict__ lp,
                                                const float* __restrict__ b_m2,
                                                const float* __restrict__ maskT,
                                                float* __restrict__ argv, int* __restrict__ argi,
                                                float* __restrict__ out, int t) {
  __shared__ float tile[32][65];
  int lane = threadIdx.x & 63, wid = threadIdx.x >> 6;
  int rg = blockIdx.x * 4 + wid;
  int nb = blockIdx.x * 32;
  if (rg < 1250) {
    int r0 = rg * 8;
    float best = -3.4e38f;
    int bi = 0;
#pragma unroll
    for (int i = 0; i < 8; ++i) {
      int r = r0 + i;
      size_t idx = (size_t)r * 64 + lane;
      float v = b_m2[r] + maskT[idx];
#pragma unroll
      for (int s = 0; s < 6; ++s) v += lp[(size_t)s * 640000 + idx];
      tile[wid * 8 + i][lane] = v;
      if (v > best) { best = v; bi = r; }  // strict >: first-max
    }
    argv[(size_t)rg * 64 + lane] = best;
    argi[(size_t)rg * 64 + lane] = bi;
  }
  __syncthreads();
  int b = threadIdx.x >> 2, q = threadIdx.x & 3;
  int nloc = q * 8;
  if (nb + nloc < NV) {  // whole 8-group valid or not (row count multiple of 8... last block has 16 rows)
    float tmp[8];
#pragma unroll
    for (int c = 0; c < 8; ++c) tmp[c] = tile[nloc + c][b];
    float4* o = (float4*)&out[((size_t)b * TT + t) * NV + nb + nloc];
    o[0] = make_float4(tmp[0], tmp[1], tmp[2], tmp[3]);
    o[1] = make_float4(tmp[4], tmp[5], tmp[6], tmp[7]);
  }
}

// ---------------- final argmax (per-batch block) + feedback ----------------
__global__ __launch_bounds__(256) void k_final(const float* __restrict__ argv,
                                               const int* __restrict__ argi,
                                               const float* __restrict__ emb,
                                               float* __restrict__ maskT, float* __restrict__ inpT,
                                               float* __restrict__ buf, float* __restrict__ bufT,
                                               float* __restrict__ out_ids, int t) {
  __shared__ float sv[256];
  __shared__ int si_[256];
  __shared__ int sid;
  int b = blockIdx.x, tid = threadIdx.x;
  float best = -3.4e38f;
  int bi = 0x7fffffff;
  for (int g = tid; g < 1250; g += 256) {
    float v = argv[(size_t)g * 64 + b];
    int idx = argi[(size_t)g * 64 + b];
    if (v > best || (v == best && idx < bi)) { best = v; bi = idx; }
  }
  sv[tid] = best;
  si_[tid] = bi;
  __syncthreads();
  for (int off = 128; off; off >>= 1) {
    if (tid < off) {
      float v2 = sv[tid + off];
      int i2 = si_[tid + off];
      if (v2 > sv[tid] || (v2 == sv[tid] && i2 < si_[tid])) { sv[tid] = v2; si_[tid] = i2; }
    }
    __syncthreads();
  }
  if (tid == 0) {
    sid = si_[0];
    out_ids[b * TT + t] = (float)si_[0];
    if (si_[0] != 1) maskT[(size_t)si_[0] * 64 + b] = MASK_VALF;  // EOS(1) stays 0
  }
  __syncthreads();
  int id = sid;
  for (int e = tid; e < 512; e += 256) {
    float v = emb[(size_t)id * 512 + e];
    inpT[e * 64 + b] = v;
    buf[((size_t)b * TT + t) * 512 + e] = v;
    bufT[(size_t)e * (TT * 64) + t * 64 + b] = v;
  }
}

extern "C" void kernel_launch(void* const* d_in, const int* in_sizes, int n_in,
                              void* d_out, int out_size, void* d_ws, size_t ws_size,
                              hipStream_t stream) {
  const float* enc = (const float*)d_in[0];
  const float* h0 = (const float*)d_in[1];
  const float* c0 = (const float*)d_in[2];
  const int* tlen = (const int*)d_in[3];
  const float* emb = (const float*)d_in[5];
  const float* w_ih = (const float*)d_in[6];
  const float* w_hh = (const float*)d_in[7];
  const float* b_ih = (const float*)d_in[8];
  const float* b_hh = (const float*)d_in[9];
  const float* w_q = (const float*)d_in[10];
  const float* b_q = (const float*)d_in[11];
  const float* w_k = (const float*)d_in[12];
  const float* b_k = (const float*)d_in[13];
  const float* w_ko = (const float*)d_in[14];
  const float* b_ko = (const float*)d_in[15];
  const float* w_m1 = (const float*)d_in[16];
  const float* b_m1 = (const float*)d_in[17];
  const float* w_m2 = (const float*)d_in[18];
  const float* b_m2 = (const float*)d_in[19];

  float* ws = (float*)d_ws;
  float* out_logits = (float*)d_out;
  float* out_ids = out_logits + (size_t)B64 * TT * NV;

  float* xt = ws + OFF_XT;  // inpT | hT
  float* hT = xt + 512 * 64;

  k_init<<<2048, 256, 0, stream>>>(h0, c0, ws);
  k_kscore<<<64, 256, 0, stream>>>(ws + OFF_BUFT, w_k, b_k, w_ko, ws + OFF_KVP, 0);

  for (int t = 0; t < TT; ++t) {
    int tv = (t < 1) ? 1 : t;
    k_gates<<<dim3(128, 12), 256, 0, stream>>>(xt, w_ih, w_hh, ws + OFF_A);
    k_lstm<<<256, 256, 0, stream>>>(ws + OFF_A, b_ih, b_hh, ws + OFF_CT, hT);
    k_q<<<dim3(32, 16), 256, 0, stream>>>(hT, w_q, ws + OFF_B);
    k_qfin<<<16, 256, 0, stream>>>(ws + OFF_B, b_q, ws + OFF_QF);
    k_flash<<<1024, 256, 0, stream>>>(enc, tlen, ws + OFF_QF, ws + OFF_FM, ws + OFF_FL,
                                      ws + OFF_B);
    k_ctx<<<64, 256, 0, stream>>>(enc, ws + OFF_FM, ws + OFF_FL, ws + OFF_B, ws + OFF_KVP, b_ko,
                                  ws + OFF_BUF, xt, ws + OFF_XT2, tv);
    k_h1<<<dim3(48, 12), 256, 0, stream>>>(ws + OFF_XT2, w_m1, ws + OFF_A);
    k_h1comb<<<384, 256, 0, stream>>>(ws + OFF_A, b_m1, ws + OFF_H1T);
    k_glog<<<dim3(313, 6), 256, 0, stream>>>(ws + OFF_H1T, w_m2, ws + OFF_A);
    k_logfin<<<313, 256, 0, stream>>>(ws + OFF_A, b_m2, ws + OFF_MASKT, ws + OFF_ARGV,
                                      (int*)(ws + OFF_ARGI), out_logits, t);
    k_final<<<64, 256, 0, stream>>>(ws + OFF_ARGV, (int*)(ws + OFF_ARGI), emb, ws + OFF_MASKT, xt,
                                    ws + OFF_BUF, ws + OFF_BUFT, out_ids, t);
    if (t < TT - 1)
      k_kscore<<<64, 256, 0, stream>>>(ws + OFF_BUFT, w_k, b_k, w_ko, ws + OFF_KVP, t);
  }
}

// Round 4
// 3327.910 us; speedup vs baseline: 3.9049x; 1.3041x over previous
//
#include <hip/hip_runtime.h>

#define B64 64
#define SE 512
#define HD 1024
#define ED 512
#define NV 10000
#define TT 20
#define MM 1536
#define MASK_VALF -10000000.0f

// ---- workspace offsets (floats); regions time-shared within a step ----
#define OFF_XT    0                    // xT [1536][64]; inpT=[0:512), hT=[512:1536)
#define OFF_CT    98304                // cT [1024][64]
#define OFF_A     163840               // REGION A (3,840,000): GPART[6][4096][64] | H1P[12][1536][64] | LP[6][10000][64]
#define OFF_B     4003840              // REGION B (1,048,576): QPART[8][1024][64] | FACC[1024][1024]
#define OFF_QF    5052416              // qf [64][1024]
#define OFF_FM    5117952              // [1024]
#define OFF_FL    5118976              // [1024]
#define OFF_XT2   5120000              // [1536][64]
#define OFF_H1T   5218304              // [1536][64]
#define OFF_ARGV  5316608              // [1250][64]
#define OFF_ARGI  5396608              // [1250][64] (int)
#define OFF_MASKT 5476608              // [10000][64]
#define OFF_BUF   6116608              // [64][20][512]
#define OFF_BUFT  6771968              // [512][20][64]
#define OFF_KVP   7427328              // [64][20][64]
// end: 7509248 floats ~= 30.0 MB

__device__ __forceinline__ float sigmoidf_(float x) { return 1.f / (1.f + expf(-x)); }

// ---------------- init ----------------
__global__ __launch_bounds__(256) void k_init(const float* __restrict__ h0,
                                              const float* __restrict__ c0,
                                              float* __restrict__ ws) {
  int idx = blockIdx.x * 256 + threadIdx.x, stride = gridDim.x * 256;
  float* inpT = ws + OFF_XT;
  float* hT = ws + OFF_XT + 512 * 64;
  float* cT = ws + OFF_CT;
  float* maskT = ws + OFF_MASKT;
  float* buf = ws + OFF_BUF;
  float* bufT = ws + OFF_BUFT;
  for (int i = idx; i < 512 * 64; i += stride) inpT[i] = 0.f;
  for (int i = idx; i < NV * 64; i += stride) maskT[i] = 0.f;
  for (int i = idx; i < B64 * TT * ED; i += stride) { buf[i] = 0.f; bufT[i] = 0.f; }
  for (int i = idx; i < HD * 64; i += stride) {
    int u = i >> 6, b = i & 63;
    hT[i] = h0[b * HD + u];
    cT[i] = c0[b * HD + u];
  }
}

// ================= generic LDS-staged thin GEMM =================
// out[r][b] partials; 32 rows/block (4 waves x 8 rows), K-tile = KT staged in LDS.
// Weight reads from LDS are wave-uniform ds_read_b128 broadcasts (no SGPR limit,
// no lgkmcnt(0) drain of scalar loads); x reads are coalesced (lane=batch).
template <int KT>
__global__ __launch_bounds__(256) void k_gemm(const float* __restrict__ W, int ldW,
                                              const float* __restrict__ x,
                                              float* __restrict__ part, int nrows, size_t psz) {
  __shared__ float wl[32][KT];
  int tid = threadIdx.x;
  int r0b = blockIdx.x * 32;
  int split = blockIdx.y;
  int k0 = split * KT;
  constexpr int NF4 = 32 * KT / 4;
  for (int i = tid; i < NF4; i += 256) {
    int r = i / (KT / 4), kk = (i % (KT / 4)) * 4;
    int gr = r0b + r;
    if (gr > nrows - 1) gr = nrows - 1;
    *(float4*)&wl[r][kk] = *(const float4*)&W[(size_t)gr * ldW + k0 + kk];
  }
  __syncthreads();
  int lane = tid & 63, wid = tid >> 6;
  const float* xp = x + (size_t)k0 * 64 + lane;
  float acc[8] = {0, 0, 0, 0, 0, 0, 0, 0};
#pragma unroll 2
  for (int k4 = 0; k4 < KT / 4; ++k4) {
    float x0 = xp[(4 * k4 + 0) * 64];
    float x1 = xp[(4 * k4 + 1) * 64];
    float x2 = xp[(4 * k4 + 2) * 64];
    float x3 = xp[(4 * k4 + 3) * 64];
#pragma unroll
    for (int i = 0; i < 8; ++i) {
      const float4 w4 = *(const float4*)&wl[wid * 8 + i][4 * k4];
      acc[i] = fmaf(w4.x, x0, acc[i]);
      acc[i] = fmaf(w4.y, x1, acc[i]);
      acc[i] = fmaf(w4.z, x2, acc[i]);
      acc[i] = fmaf(w4.w, x3, acc[i]);
    }
  }
  int r0 = r0b + wid * 8;
  float* o = part + (size_t)split * psz + (size_t)r0 * 64 + lane;
#pragma unroll
  for (int i = 0; i < 8; ++i)
    if (r0 + i < nrows) o[i * 64] = acc[i];
}

// ---------------- LSTM gates GEMM (LDS-staged, 6 K-splits of 256) ----------------
__global__ __launch_bounds__(256) void k_gates(const float* __restrict__ xt,
                                               const float* __restrict__ w_ih,
                                               const float* __restrict__ w_hh,
                                               float* __restrict__ gpart) {
  __shared__ float wl[32][256];
  int tid = threadIdx.x;
  int r0b = blockIdx.x * 32;
  int y = blockIdx.y;  // 0..5
  const float* W;
  int ldW, k0, xoff;
  if (y < 2) { W = w_ih; ldW = 512; k0 = y * 256; xoff = k0; }
  else { W = w_hh; ldW = 1024; k0 = (y - 2) * 256; xoff = 512 + k0; }
  for (int i = tid; i < 32 * 64; i += 256) {
    int r = i >> 6, kk = (i & 63) * 4;
    *(float4*)&wl[r][kk] = *(const float4*)&W[(size_t)(r0b + r) * ldW + k0 + kk];
  }
  __syncthreads();
  int lane = tid & 63, wid = tid >> 6;
  const float* xp = xt + (size_t)xoff * 64 + lane;
  float acc[8] = {0, 0, 0, 0, 0, 0, 0, 0};
#pragma unroll 2
  for (int k4 = 0; k4 < 64; ++k4) {
    float x0 = xp[(4 * k4 + 0) * 64];
    float x1 = xp[(4 * k4 + 1) * 64];
    float x2 = xp[(4 * k4 + 2) * 64];
    float x3 = xp[(4 * k4 + 3) * 64];
#pragma unroll
    for (int i = 0; i < 8; ++i) {
      const float4 w4 = *(const float4*)&wl[wid * 8 + i][4 * k4];
      acc[i] = fmaf(w4.x, x0, acc[i]);
      acc[i] = fmaf(w4.y, x1, acc[i]);
      acc[i] = fmaf(w4.z, x2, acc[i]);
      acc[i] = fmaf(w4.w, x3, acc[i]);
    }
  }
  int r0 = r0b + wid * 8;
  float* o = gpart + ((size_t)y * 262144 + (size_t)r0 * 64) + lane;
#pragma unroll
  for (int i = 0; i < 8; ++i) o[i * 64] = acc[i];
}

// ---------------- LSTM pointwise (combine 6 partials) ----------------
__global__ __launch_bounds__(256) void k_lstm(const float* __restrict__ gpart,
                                              const float* __restrict__ b_ih,
                                              const float* __restrict__ b_hh,
                                              float* __restrict__ cT, float* __restrict__ hT) {
  int i = blockIdx.x * 256 + threadIdx.x;  // 65536
  int u = i >> 6, b = i & 63;
  float g4[4];
#pragma unroll
  for (int gi = 0; gi < 4; ++gi) {
    int r = gi * 1024 + u;
    float v = b_ih[r] + b_hh[r];
#pragma unroll
    for (int y = 0; y < 6; ++y) v += gpart[(size_t)y * 262144 + (size_t)r * 64 + b];
    g4[gi] = v;
  }
  float c = cT[i];
  float cn = sigmoidf_(g4[1]) * c + sigmoidf_(g4[0]) * tanhf(g4[2]);
  float hn = sigmoidf_(g4[3]) * tanhf(cn);
  cT[i] = cn;
  hT[i] = hn;
}

// ---------------- combine q splits + b_q -> qf[b][h] (transposed via LDS) ----------------
__global__ __launch_bounds__(256) void k_qfin(const float* __restrict__ qpart,
                                              const float* __restrict__ b_q,
                                              float* __restrict__ qf) {
  __shared__ float tile[64][65];
  int h0 = blockIdx.x * 64;
  int lane = threadIdx.x & 63, hrow = threadIdx.x >> 6;
#pragma unroll
  for (int p = 0; p < 16; ++p) {
    int hl = p * 4 + hrow;
    int h = h0 + hl;
    float v = b_q[h];
#pragma unroll
    for (int s = 0; s < 8; ++s) v += qpart[((size_t)s * 1024 + h) * 64 + lane];
    tile[hl][lane] = v;
  }
  __syncthreads();
#pragma unroll
  for (int p = 0; p < 16; ++p) {
    int b = p * 4 + hrow;
    qf[(size_t)b * 1024 + h0 + lane] = tile[lane][b];
  }
}

// ---------------- flash attention: pair-processed, software-pipelined ----------------
__global__ __launch_bounds__(256) void k_flash(const float* __restrict__ enc,
                                               const int* __restrict__ tlen,
                                               const float* __restrict__ qf,
                                               float* __restrict__ fm, float* __restrict__ fl,
                                               float* __restrict__ facc) {
  __shared__ float lacc[4][1024];
  __shared__ float lml[4][2];
  int b = blockIdx.x >> 4, split = blockIdx.x & 15;
  int tid = threadIdx.x, lane = tid & 63, wid = tid >> 6;
  int len = tlen[b];
  float qv[16];
#pragma unroll
  for (int j = 0; j < 4; ++j) {
    float4 tq = *(const float4*)&qf[(size_t)b * 1024 + j * 256 + lane * 4];
    qv[4 * j + 0] = tq.x; qv[4 * j + 1] = tq.y; qv[4 * j + 2] = tq.z; qv[4 * j + 3] = tq.w;
  }
  const float* base = enc + (size_t)b * SE * HD;
  int s0 = split * 32 + wid * 8;
  int nr = len - s0;
  nr = nr < 0 ? 0 : (nr > 8 ? 8 : nr);
  int npair = nr >> 1;

  float4 cA[4], cB[4], nA[4], nB[4];
  float m = -1e30f, l = 0.f, acc[16];
#pragma unroll
  for (int j = 0; j < 16; ++j) acc[j] = 0.f;

#define LOADROW(d, s)                                            \
  {                                                              \
    const float4* rp = (const float4*)(base + (size_t)(s)*HD) + lane; \
    d[0] = rp[0]; d[1] = rp[64]; d[2] = rp[128]; d[3] = rp[192]; \
  }

  if (npair > 0) { LOADROW(cA, s0); LOADROW(cB, s0 + 1); }
  for (int p = 0; p < npair; ++p) {
    if (p + 1 < npair) {
      LOADROW(nA, s0 + 2 * p + 2);
      LOADROW(nB, s0 + 2 * p + 3);
    } else if (nr & 1) {
      LOADROW(nA, s0 + nr - 1);
    }
    float d0 = 0.f, d1 = 0.f;
#pragma unroll
    for (int j = 0; j < 4; ++j) {
      d0 = fmaf(qv[4 * j + 0], cA[j].x, d0); d1 = fmaf(qv[4 * j + 0], cB[j].x, d1);
      d0 = fmaf(qv[4 * j + 1], cA[j].y, d0); d1 = fmaf(qv[4 * j + 1], cB[j].y, d1);
      d0 = fmaf(qv[4 * j + 2], cA[j].z, d0); d1 = fmaf(qv[4 * j + 2], cB[j].z, d1);
      d0 = fmaf(qv[4 * j + 3], cA[j].w, d0); d1 = fmaf(qv[4 * j + 3], cB[j].w, d1);
    }
#pragma unroll
    for (int off = 32; off; off >>= 1) { d0 += __shfl_xor(d0, off, 64); d1 += __shfl_xor(d1, off, 64); }
    d0 = __shfl(d0, 0, 64);
    d1 = __shfl(d1, 0, 64);
    float mn = fmaxf(m, fmaxf(d0, d1));
    float sc = expf(m - mn), p0 = expf(d0 - mn), p1 = expf(d1 - mn);
    l = l * sc + p0 + p1;
#pragma unroll
    for (int j = 0; j < 4; ++j) {
      acc[4 * j + 0] = fmaf(p1, cB[j].x, fmaf(p0, cA[j].x, acc[4 * j + 0] * sc));
      acc[4 * j + 1] = fmaf(p1, cB[j].y, fmaf(p0, cA[j].y, acc[4 * j + 1] * sc));
      acc[4 * j + 2] = fmaf(p1, cB[j].z, fmaf(p0, cA[j].z, acc[4 * j + 2] * sc));
      acc[4 * j + 3] = fmaf(p1, cB[j].w, fmaf(p0, cA[j].w, acc[4 * j + 3] * sc));
    }
    m = mn;
#pragma unroll
    for (int j = 0; j < 4; ++j) { cA[j] = nA[j]; cB[j] = nB[j]; }
  }
  if (nr & 1) {
    if (npair == 0) LOADROW(cA, s0);
    float d0 = 0.f;
#pragma unroll
    for (int j = 0; j < 4; ++j) {
      d0 = fmaf(qv[4 * j + 0], cA[j].x, d0);
      d0 = fmaf(qv[4 * j + 1], cA[j].y, d0);
      d0 = fmaf(qv[4 * j + 2], cA[j].z, d0);
      d0 = fmaf(qv[4 * j + 3], cA[j].w, d0);
    }
#pragma unroll
    for (int off = 32; off; off >>= 1) d0 += __shfl_xor(d0, off, 64);
    d0 = __shfl(d0, 0, 64);
    float mn = fmaxf(m, d0);
    float sc = expf(m - mn), p0 = expf(d0 - mn);
    l = l * sc + p0;
#pragma unroll
    for (int j = 0; j < 4; ++j) {
      acc[4 * j + 0] = fmaf(p0, cA[j].x, acc[4 * j + 0] * sc);
      acc[4 * j + 1] = fmaf(p0, cA[j].y, acc[4 * j + 1] * sc);
      acc[4 * j + 2] = fmaf(p0, cA[j].z, acc[4 * j + 2] * sc);
      acc[4 * j + 3] = fmaf(p0, cA[j].w, acc[4 * j + 3] * sc);
    }
    m = mn;
  }
#undef LOADROW
#pragma unroll
  for (int j = 0; j < 4; ++j)
    *(float4*)&lacc[wid][j * 256 + lane * 4] =
        make_float4(acc[4 * j], acc[4 * j + 1], acc[4 * j + 2], acc[4 * j + 3]);
  if (lane == 0) { lml[wid][0] = m; lml[wid][1] = l; }
  __syncthreads();
  float M = fmaxf(fmaxf(lml[0][0], lml[1][0]), fmaxf(lml[2][0], lml[3][0]));
  float w0 = expf(lml[0][0] - M), w1 = expf(lml[1][0] - M);
  float w2 = expf(lml[2][0] - M), w3 = expf(lml[3][0] - M);
  float L = w0 * lml[0][1] + w1 * lml[1][1] + w2 * lml[2][1] + w3 * lml[3][1];
  int p = b * 16 + split;
  for (int h = tid; h < 1024; h += 256)
    facc[(size_t)p * 1024 + h] =
        w0 * lacc[0][h] + w1 * lacc[1][h] + w2 * lacc[2][h] + w3 * lacc[3][h];
  if (tid == 0) { fm[p] = M; fl[p] = L; }
}

// ---------------- fused: flash combine + history softmax -> full xT2 ----------------
__global__ __launch_bounds__(256) void k_ctx(const float* __restrict__ enc,
                                             const float* __restrict__ fm,
                                             const float* __restrict__ fl,
                                             const float* __restrict__ facc,
                                             const float* __restrict__ kvp,
                                             const float* __restrict__ b_ko,
                                             const float* __restrict__ buf,
                                             const float* __restrict__ inpT,
                                             float* __restrict__ xT2, int tv) {
  __shared__ float pw[TT];
  int b = blockIdx.x, tid = threadIdx.x;
  if (tid < tv) {
    float s = b_ko[0];
    for (int g = 0; g < 64; ++g) s += kvp[((size_t)g * TT + tid) * 64 + b];
    pw[tid] = s;
  }
  __syncthreads();
  float mx = -1e30f;
  for (int k = 0; k < tv; ++k) mx = fmaxf(mx, pw[k]);
  float den = 0.f;
  for (int k = 0; k < tv; ++k) den += expf(pw[k] - mx);
  float invd = 1.f / den;
  __syncthreads();
  if (tid < tv) pw[tid] = expf(pw[tid] - mx) * invd;
  __syncthreads();
  float M = -1e30f;
#pragma unroll
  for (int k = 0; k < 16; ++k) M = fmaxf(M, fm[b * 16 + k]);
  float w[16];
  float L = 0.f;
#pragma unroll
  for (int k = 0; k < 16; ++k) {
    w[k] = expf(fm[b * 16 + k] - M);
    L += w[k] * fl[b * 16 + k];
  }
  float inv = 1.f / L;
  for (int h = tid; h < 1024; h += 256) {
    float s = 0.f;
#pragma unroll
    for (int k = 0; k < 16; ++k) s += w[k] * facc[(size_t)(b * 16 + k) * 1024 + h];
    xT2[h * 64 + b] = enc[(size_t)b * SE * HD + h] + s * inv;
  }
  for (int e = tid; e < 512; e += 256) {
    float a = 0.f;
    for (int k = 0; k < tv; ++k) a += pw[k] * buf[((size_t)b * TT + k) * 512 + e];
    xT2[(1024 + e) * 64 + b] = inpT[e * 64 + b] + a;
  }
}

// ---------------- incremental history score for buf column j ----------------
__global__ __launch_bounds__(256) void k_kscore(const float* __restrict__ bufT,
                                                const float* __restrict__ w_k,
                                                const float* __restrict__ b_k,
                                                const float* __restrict__ w_ko,
                                                float* __restrict__ kvp, int j) {
  __shared__ float sacc[4][8][64];
  int lane = threadIdx.x & 63, wid = threadIdx.x >> 6;
  int ug = blockIdx.x;  // 0..63
  int u0 = ug * 8;
  int k0 = wid * 128;
  const float* xp = bufT + (size_t)j * 64 + lane;
  float acc[8] = {0, 0, 0, 0, 0, 0, 0, 0};
  for (int k4 = 0; k4 < 32; ++k4) {
    int e = k0 + 4 * k4;
    float x0 = xp[(size_t)(e + 0) * (TT * 64)];
    float x1 = xp[(size_t)(e + 1) * (TT * 64)];
    float x2 = xp[(size_t)(e + 2) * (TT * 64)];
    float x3 = xp[(size_t)(e + 3) * (TT * 64)];
#pragma unroll
    for (int i = 0; i < 8; ++i) {
      const float4 w4 = *(const float4*)&w_k[(size_t)(u0 + i) * 512 + e];
      acc[i] = fmaf(w4.x, x0, acc[i]);
      acc[i] = fmaf(w4.y, x1, acc[i]);
      acc[i] = fmaf(w4.z, x2, acc[i]);
      acc[i] = fmaf(w4.w, x3, acc[i]);
    }
  }
#pragma unroll
  for (int i = 0; i < 8; ++i) sacc[wid][i][lane] = acc[i];
  __syncthreads();
  if (wid == 0) {
    float kp = 0.f;
#pragma unroll
    for (int i = 0; i < 8; ++i) {
      float tot = b_k[u0 + i] + sacc[0][i][lane] + sacc[1][i][lane] + sacc[2][i][lane] +
                  sacc[3][i][lane];
      kp += fmaxf(tot, 0.f) * w_ko[u0 + i];
    }
    kvp[((size_t)ug * TT + j) * 64 + lane] = kp;
  }
}

__global__ __launch_bounds__(256) void k_h1comb(const float* __restrict__ h1part,
                                                const float* __restrict__ b_m1,
                                                float* __restrict__ h1T) {
  int i = blockIdx.x * 256 + threadIdx.x;  // 98304
  int r = i >> 6;
  float v = b_m1[r];
#pragma unroll
  for (int s = 0; s < 12; ++s) v += h1part[(size_t)s * 98304 + i];
  h1T[i] = fmaxf(v, 0.f);
}

// ---------------- logits finish: combine + bias + mask + argmax + transposed out-write ----------------
__global__ __launch_bounds__(256) void k_logfin(const float* __restrict__ lp,
                                                const float* __restrict__ b_m2,
                                                const float* __restrict__ maskT,
                                                float* __restrict__ argv, int* __restrict__ argi,
                                                float* __restrict__ out, int t) {
  __shared__ float tile[32][65];
  int lane = threadIdx.x & 63, wid = threadIdx.x >> 6;
  int rg = blockIdx.x * 4 + wid;
  int nb = blockIdx.x * 32;
  if (rg < 1250) {
    int r0 = rg * 8;
    float best = -3.4e38f;
    int bi = 0;
#pragma unroll
    for (int i = 0; i < 8; ++i) {
      int r = r0 + i;
      size_t idx = (size_t)r * 64 + lane;
      float v = b_m2[r] + maskT[idx];
#pragma unroll
      for (int s = 0; s < 6; ++s) v += lp[(size_t)s * 640000 + idx];
      tile[wid * 8 + i][lane] = v;
      if (v > best) { best = v; bi = r; }  // strict >: first-max
    }
    argv[(size_t)rg * 64 + lane] = best;
    argi[(size_t)rg * 64 + lane] = bi;
  }
  __syncthreads();
  int b = threadIdx.x >> 2, q = threadIdx.x & 3;
  int nloc = q * 8;
  if (nb + nloc < NV) {
    float tmp[8];
#pragma unroll
    for (int c = 0; c < 8; ++c) tmp[c] = tile[nloc + c][b];
    float4* o = (float4*)&out[((size_t)b * TT + t) * NV + nb + nloc];
    o[0] = make_float4(tmp[0], tmp[1], tmp[2], tmp[3]);
    o[1] = make_float4(tmp[4], tmp[5], tmp[6], tmp[7]);
  }
}

// ---------------- final argmax (per-batch block) + feedback ----------------
__global__ __launch_bounds__(256) void k_final(const float* __restrict__ argv,
                                               const int* __restrict__ argi,
                                               const float* __restrict__ emb,
                                               float* __restrict__ maskT, float* __restrict__ inpT,
                                               float* __restrict__ buf, float* __restrict__ bufT,
                                               float* __restrict__ out_ids, int t) {
  __shared__ float sv[256];
  __shared__ int si_[256];
  __shared__ int sid;
  int b = blockIdx.x, tid = threadIdx.x;
  float best = -3.4e38f;
  int bi = 0x7fffffff;
  for (int g = tid; g < 1250; g += 256) {
    float v = argv[(size_t)g * 64 + b];
    int idx = argi[(size_t)g * 64 + b];
    if (v > best || (v == best && idx < bi)) { best = v; bi = idx; }
  }
  sv[tid] = best;
  si_[tid] = bi;
  __syncthreads();
  for (int off = 128; off; off >>= 1) {
    if (tid < off) {
      float v2 = sv[tid + off];
      int i2 = si_[tid + off];
      if (v2 > sv[tid] || (v2 == sv[tid] && i2 < si_[tid])) { sv[tid] = v2; si_[tid] = i2; }
    }
    __syncthreads();
  }
  if (tid == 0) {
    sid = si_[0];
    out_ids[b * TT + t] = (float)si_[0];
    if (si_[0] != 1) maskT[(size_t)si_[0] * 64 + b] = MASK_VALF;  // EOS(1) stays 0
  }
  __syncthreads();
  int id = sid;
  for (int e = tid; e < 512; e += 256) {
    float v = emb[(size_t)id * 512 + e];
    inpT[e * 64 + b] = v;
    buf[((size_t)b * TT + t) * 512 + e] = v;
    bufT[(size_t)e * (TT * 64) + t * 64 + b] = v;
  }
}

extern "C" void kernel_launch(void* const* d_in, const int* in_sizes, int n_in,
                              void* d_out, int out_size, void* d_ws, size_t ws_size,
                              hipStream_t stream) {
  const float* enc = (const float*)d_in[0];
  const float* h0 = (const float*)d_in[1];
  const float* c0 = (const float*)d_in[2];
  const int* tlen = (const int*)d_in[3];
  const float* emb = (const float*)d_in[5];
  const float* w_ih = (const float*)d_in[6];
  const float* w_hh = (const float*)d_in[7];
  const float* b_ih = (const float*)d_in[8];
  const float* b_hh = (const float*)d_in[9];
  const float* w_q = (const float*)d_in[10];
  const float* b_q = (const float*)d_in[11];
  const float* w_k = (const float*)d_in[12];
  const float* b_k = (const float*)d_in[13];
  const float* w_ko = (const float*)d_in[14];
  const float* b_ko = (const float*)d_in[15];
  const float* w_m1 = (const float*)d_in[16];
  const float* b_m1 = (const float*)d_in[17];
  const float* w_m2 = (const float*)d_in[18];
  const float* b_m2 = (const float*)d_in[19];

  float* ws = (float*)d_ws;
  float* out_logits = (float*)d_out;
  float* out_ids = out_logits + (size_t)B64 * TT * NV;

  float* xt = ws + OFF_XT;  // inpT | hT
  float* hT = xt + 512 * 64;

  k_init<<<2048, 256, 0, stream>>>(h0, c0, ws);
  k_kscore<<<64, 256, 0, stream>>>(ws + OFF_BUFT, w_k, b_k, w_ko, ws + OFF_KVP, 0);

  for (int t = 0; t < TT; ++t) {
    int tv = (t < 1) ? 1 : t;
    k_gates<<<dim3(128, 6), 256, 0, stream>>>(xt, w_ih, w_hh, ws + OFF_A);
    k_lstm<<<256, 256, 0, stream>>>(ws + OFF_A, b_ih, b_hh, ws + OFF_CT, hT);
    k_gemm<128><<<dim3(32, 8), 256, 0, stream>>>(w_q, 1024, hT, ws + OFF_B, 1024, 65536);
    k_qfin<<<16, 256, 0, stream>>>(ws + OFF_B, b_q, ws + OFF_QF);
    k_flash<<<1024, 256, 0, stream>>>(enc, tlen, ws + OFF_QF, ws + OFF_FM, ws + OFF_FL,
                                      ws + OFF_B);
    k_ctx<<<64, 256, 0, stream>>>(enc, ws + OFF_FM, ws + OFF_FL, ws + OFF_B, ws + OFF_KVP, b_ko,
                                  ws + OFF_BUF, xt, ws + OFF_XT2, tv);
    k_gemm<128><<<dim3(48, 12), 256, 0, stream>>>(w_m1, MM, ws + OFF_XT2, ws + OFF_A, MM, 98304);
    k_h1comb<<<384, 256, 0, stream>>>(ws + OFF_A, b_m1, ws + OFF_H1T);
    k_gemm<256><<<dim3(313, 6), 256, 0, stream>>>(w_m2, MM, ws + OFF_H1T, ws + OFF_A, NV, 640000);
    k_logfin<<<313, 256, 0, stream>>>(ws + OFF_A, b_m2, ws + OFF_MASKT, ws + OFF_ARGV,
                                      (int*)(ws + OFF_ARGI), out_logits, t);
    k_final<<<64, 256, 0, stream>>>(ws + OFF_ARGV, (int*)(ws + OFF_ARGI), emb, ws + OFF_MASKT, xt,
                                    ws + OFF_BUF, ws + OFF_BUFT, out_ids, t);
    if (t < TT - 1)
      k_kscore<<<64, 256, 0, stream>>>(ws + OFF_BUFT, w_k, b_k, w_ko, ws + OFF_KVP, t);
  }
}